// Round 15
// baseline (680.433 us; speedup 1.0000x reference)
//
#include <hip/hip_runtime.h>
#include <hip/hip_bf16.h>

// NonLocal block == flash attention (4 heads, N=4096, D=128) + 1x1-conv GEMMs.
// Round 15: flash12 = pair-split flash. Wave pairs split the D=128 contraction
// (QK) and the j-range (softmax+PV); partial S exchanged via LDS (bf16); oacc
// pair-summed at end with exact m-rescale. 4 waves/SIMD, 16 waves/CU.

typedef float f32x4 __attribute__((ext_vector_type(4)));
typedef float f32x16 __attribute__((ext_vector_type(16)));
typedef short s16x8 __attribute__((ext_vector_type(8)));

#define B_  4
#define C_  256
#define CI_ 128
#define N_  4096

#define OFF_Q    (8ull  << 20)
#define OFF_K    (12ull << 20)
#define OFF_G    (16ull << 20)
#define OFF_WQK  (24ull << 20)
#define OFF_WG   (OFF_WQK + 131072)
#define OFF_WOUT (OFF_WG  + 65536)
#define OFF_BQK  (OFF_WOUT + 65536)
#define OFF_BG   (OFF_BQK + 1024)
#define OFF_BOUT (OFF_BG  + 512)
#define OFF_END  (OFF_BOUT + 1024)

__device__ inline f32x4 mfma16(s16x8 a, s16x8 b, f32x4 c) {
    return __builtin_amdgcn_mfma_f32_16x16x32_bf16(a, b, c, 0, 0, 0);
}
__device__ inline f32x16 mfma32(s16x8 a, s16x8 b, f32x16 c) {
    return __builtin_amdgcn_mfma_f32_32x32x16_bf16(a, b, c, 0, 0, 0);
}
__device__ inline s16x8 ld8(const __hip_bfloat16* p) { return *(const s16x8*)p; }
__device__ inline float b2f(short u) {
    return __uint_as_float(((unsigned int)(unsigned short)u) << 16);
}
__device__ inline unsigned int pk2(float a, float b) {
    __hip_bfloat162 h;
    h.x = __float2bfloat16(a); h.y = __float2bfloat16(b);
    return *(unsigned int*)&h;
}
__device__ inline void gload_lds16(const void* g, void* l) {
    __builtin_amdgcn_global_load_lds(
        (const __attribute__((address_space(1))) unsigned int*)g,
        (__attribute__((address_space(3))) unsigned int*)l, 16, 0, 0);
}
__device__ inline float fexp2(float x) { return __builtin_amdgcn_exp2f(x); }

// ---------------- weight prep (frozen) -------------------------------------
__global__ void prep_weights(const float* wg, const float* bg,
                             const float* wt, const float* bt,
                             const float* wp, const float* bp,
                             const float* wo, const float* bo, char* ws) {
    __hip_bfloat16* Wqk  = (__hip_bfloat16*)(ws + OFF_WQK);
    __hip_bfloat16* Wg   = (__hip_bfloat16*)(ws + OFF_WG);
    __hip_bfloat16* Wout = (__hip_bfloat16*)(ws + OFF_WOUT);
    float* Bqk  = (float*)(ws + OFF_BQK);
    float* Bg   = (float*)(ws + OFF_BG);
    float* Bout = (float*)(ws + OFF_BOUT);
    const float rs = 0.08838834764831845f * 1.4426950408889634f;
    int idx = blockIdx.x * 256 + threadIdx.x;
    if (idx < 65536) {
        int r = idx >> 8, c = idx & 255;
        float v = (r < 128) ? wt[r * 256 + c] * rs : wp[(r - 128) * 256 + c];
        Wqk[idx] = __float2bfloat16(v);
    }
    if (idx < 32768) {
        Wg[idx]   = __float2bfloat16(wg[idx]);
        Wout[idx] = __float2bfloat16(wo[idx]);
    }
    if (idx < 256) { Bqk[idx] = (idx < 128) ? bt[idx] * rs : bp[idx - 128]; Bout[idx] = bo[idx]; }
    if (idx < 128) Bg[idx] = bg[idx];
}

// ---------------- fused transpose + projection (frozen from R12) -----------
__global__ __launch_bounds__(256) void proj(const float* x, char* ws) {
    const __hip_bfloat16* Wqk = (const __hip_bfloat16*)(ws + OFF_WQK);
    const __hip_bfloat16* Wg  = (const __hip_bfloat16*)(ws + OFF_WG);
    const float* Bqk = (const float*)(ws + OFF_BQK);
    const float* Bg  = (const float*)(ws + OFF_BG);
    __hip_bfloat16* Q  = (__hip_bfloat16*)(ws + OFF_Q);
    __hip_bfloat16* Kb = (__hip_bfloat16*)(ws + OFF_K);
    __hip_bfloat16* G  = (__hip_bfloat16*)(ws + OFF_G);

    __shared__ char at[32 * 512];

    int b = blockIdx.y, n0 = blockIdx.x * 32;
    int t = threadIdx.x;
    int w = t >> 6, l = t & 63, lr = l & 15, lg = l >> 4;

    {
        int n4 = (t & 7) * 4;
        int cp = t >> 3;
        const float* xb = x + ((size_t)b * C_) * N_ + n0 + n4;
#pragma unroll
        for (int p = 0; p < 4; p++) {
            int c0 = (p * 32 + cp) * 2;
            f32x4 vA = *(const f32x4*)(xb + (size_t)c0 * N_);
            f32x4 vB = *(const f32x4*)(xb + (size_t)(c0 + 1) * N_);
            int slot = c0 >> 3, coff = (c0 & 7) << 1;
#pragma unroll
            for (int i = 0; i < 4; i++) {
                int n = n4 + i;
                *(unsigned int*)(&at[n * 512 + ((slot ^ (n & 7)) << 4) + coff]) =
                    pk2(vA[i], vB[i]);
            }
        }
    }
    __syncthreads();

    f32x4 acc[4][2] = {};
    f32x4 accg[2][2] = {};
    int o0q = w * 64, o0g = w * 32;
#pragma unroll
    for (int kk = 0; kk < 8; kk++) {
        s16x8 a[2];
#pragma unroll
        for (int nf = 0; nf < 2; nf++) {
            int row = nf * 16 + lr;
            int s = (4 * kk + lg) ^ (row & 7);
            a[nf] = *(const s16x8*)(&at[row * 512 + s * 16]);
        }
#pragma unroll
        for (int of = 0; of < 4; of++) {
            s16x8 bb = ld8(Wqk + (size_t)(o0q + 16 * of + lr) * C_ + kk * 32 + lg * 8);
            acc[of][0] = mfma16(a[0], bb, acc[of][0]);
            acc[of][1] = mfma16(a[1], bb, acc[of][1]);
        }
#pragma unroll
        for (int og = 0; og < 2; og++) {
            s16x8 ag = ld8(Wg + (size_t)(o0g + 16 * og + lr) * C_ + kk * 32 + lg * 8);
            accg[og][0] = mfma16(ag, a[0], accg[og][0]);
            accg[og][1] = mfma16(ag, a[1], accg[og][1]);
        }
    }
#pragma unroll
    for (int of = 0; of < 4; of++) {
        int o = o0q + 16 * of + lr;
        float bias = Bqk[o];
#pragma unroll
        for (int nf = 0; nf < 2; nf++) {
#pragma unroll
            for (int i = 0; i < 4; i++) {
                int n = n0 + 16 * nf + lg * 4 + i;
                float v = acc[of][nf][i] + bias;
                if (o < 128) Q [(size_t)(b * N_ + n) * CI_ + o]         = __float2bfloat16(v);
                else         Kb[(size_t)(b * N_ + n) * CI_ + (o - 128)] = __float2bfloat16(v);
            }
        }
    }
#pragma unroll
    for (int og = 0; og < 2; og++) {
#pragma unroll
        for (int i = 0; i < 4; i++) {
            int o = o0g + 16 * og + lg * 4 + i;
            float bias = Bg[o];
#pragma unroll
            for (int nf = 0; nf < 2; nf++) {
                int n = n0 + 16 * nf + lr;
                G[(size_t)(b * CI_ + o) * N_ + n] = __float2bfloat16(accg[og][nf][i] + bias);
            }
        }
    }
}

// ---------------- flash12: pair-split (k-half QK, j-half softmax/PV) -------
// Block 256 = 2 pairs; pair p covers q0 = qt*64 + p*32 (32 q). Wave h = w&1.
// LDS: kbuf 2x8K | vbuf 2x8K | xbuf 4x1K (S exchange) | pbuf 4x1K (P frags).
__global__ __launch_bounds__(256, 4) void flash12(char* ws, int nchunk,
                                                  unsigned long long off_part,
                                                  unsigned long long off_ml) {
    const __hip_bfloat16* Q  = (const __hip_bfloat16*)(ws + OFF_Q);
    const __hip_bfloat16* Kb = (const __hip_bfloat16*)(ws + OFF_K);
    const __hip_bfloat16* G  = (const __hip_bfloat16*)(ws + OFF_G);
    __hip_bfloat16* OP = (__hip_bfloat16*)(ws + off_part);
    float* ML = (float*)(ws + off_ml);

    __shared__ __attribute__((aligned(64))) char smem[40960];
    char* xb  = smem + 32768;   // [4 waves][1024]
    char* pb_ = smem + 36864;   // [4 waves][1024]

    int L = blockIdx.x;
    int npairs = B_ * nchunk;
    int pr = L % npairs, qt = L / npairs;
    int b = pr / nchunk, cz = pr % nchunk;
    int CH = N_ / nchunk;
    int jb = cz * CH, je = jb + CH;

    int w = threadIdx.x >> 6, l = threadIdx.x & 63;
    int cl = l & 31, hi = l >> 5;
    int p = w >> 1, h = w & 1;
    int q0 = qt * 64 + p * 32;
    int kkey = (l & 7) << 4;
    int vkey = (l >> 1) & 3;
    int pkey = (cl >> 2) & 1;          // pbuf slot swizzle key
    char* myx = xb + w * 1024;
    char* pax = xb + (w ^ 1) * 1024;
    char* mypb = pb_ + w * 1024;

    auto STAGE = [&](int pb2, int j0_) {
#pragma unroll
        for (int i = 0; i < 2; i++) {
            int row = w * 8 + i * 4 + (l >> 4);
            int bcol = ((l & 15) << 4) ^ ((row & 7) << 4);
            const char* src = (const char*)Kb + (((size_t)b * N_ + j0_ + row) << 8) + bcol;
            gload_lds16(src, smem + pb2 * 8192 + (w * 8 + i * 4) * 256);
        }
#pragma unroll
        for (int i = 0; i < 2; i++) {
            int c = w * 32 + i * 16 + (l >> 2);
            int srcslot = (l & 3) ^ ((l >> 3) & 3);
            const char* src = (const char*)G + ((((size_t)b * CI_ + c) * N_ + j0_) << 1)
                              + (srcslot << 4);
            gload_lds16(src, smem + 16384 + pb2 * 8192 + (w * 32 + i * 16) * 64);
        }
    };

    // Q k-half as B-operand: lane holds Q[k = h*64 + st*16 + hi*8 + e][q0+cl]
    s16x8 qb[4];
    {
        const __hip_bfloat16* qrow = Q + ((size_t)b * N_ + q0 + cl) * CI_ + h * 64 + hi * 8;
#pragma unroll
        for (int st = 0; st < 4; st++) qb[st] = ld8(qrow + st * 16);
    }

    f32x16 oacc[4] = {};
    float m_i = 0.f, lsum = 0.f;

    STAGE(0, jb);
    __syncthreads();
    int pb = 0;
    int sndbase = (h ^ 1) * 8, kpbase = h * 8;

    for (int j0 = jb; j0 < je; j0 += 32) {
        if (j0 + 32 < je) STAGE(pb ^ 1, j0 + 32);
        const char* kbb = smem + pb * 8192;
        const char* vbb = smem + 16384 + pb * 8192;
        // partial S^T over my k-half (4-deep chain)
        f32x16 s = {};
        __builtin_amdgcn_s_setprio(1);
#pragma unroll
        for (int st = 0; st < 4; st++) {
            s16x8 kf = *(const s16x8*)(kbb + cl * 256 +
                                       ((((h << 3) + (st << 1) + hi) << 4) ^ kkey));
            s = mfma32(kf, qb[st], s);
        }
        __builtin_amdgcn_s_setprio(0);
        // send partner's r-half (bf16) via xbuf
        {
            union { unsigned int u[4]; s16x8 v; } snd;
#pragma unroll
            for (int i = 0; i < 4; i++)
                snd.u[i] = pk2(s[sndbase + 2 * i], s[sndbase + 2 * i + 1]);
            *(s16x8*)(myx + l * 16) = snd.v;
        }
        __syncthreads();
        // receive partner's partial for my kept r-half, add
        {
            s16x8 rcv = *(const s16x8*)(pax + l * 16);
#pragma unroll
            for (int i = 0; i < 8; i++) s[kpbase + i] += b2f(rcv[i]);
        }
        if (j0 == jb) {
            float tm = s[kpbase];
#pragma unroll
            for (int i = 1; i < 8; i++) tm = fmaxf(tm, s[kpbase + i]);
            tm = fmaxf(tm, __shfl_xor(tm, 32));
            m_i = tm;
        }
        float kv[8];
        float acc0 = 0.f;
#pragma unroll
        for (int i = 0; i < 8; i++) { kv[i] = fexp2(s[kpbase + i] - m_i); acc0 += kv[i]; }
        lsum += acc0;
        // pack P to pbuf (row cl, 32B): j-half slots swizzled by pkey
        {
            char* prow = mypb + cl * 32;
            *(unsigned int*)(prow + (pkey << 4) + 8 * hi)       = pk2(kv[0], kv[1]);
            *(unsigned int*)(prow + (pkey << 4) + 8 * hi + 4)   = pk2(kv[2], kv[3]);
            *(unsigned int*)(prow + ((1 ^ pkey) << 4) + 8 * hi)     = pk2(kv[4], kv[5]);
            *(unsigned int*)(prow + ((1 ^ pkey) << 4) + 8 * hi + 4) = pk2(kv[6], kv[7]);
        }
        s16x8 pa = *(const s16x8*)(mypb + cl * 32 + ((hi ^ pkey) << 4));
        // PV over my j-half: V[j = 16h + hi*8 + e][c]
        __builtin_amdgcn_s_setprio(1);
#pragma unroll
        for (int cb = 0; cb < 4; cb++) {
            s16x8 vf = *(const s16x8*)(vbb + ((cb * 32 + cl) << 6) +
                                       ((((h << 1) + hi) ^ vkey) << 4));
            oacc[cb] = mfma32(pa, vf, oacc[cb]);
        }
        __builtin_amdgcn_s_setprio(0);
        __syncthreads();
        pb ^= 1;
    }
    // ---- pair reduction ----
    lsum += __shfl_xor(lsum, 32);
    if (hi == 0) {
        *(float*)(myx + cl * 8)     = m_i;
        *(float*)(myx + cl * 8 + 4) = lsum;
    }
    __syncthreads();
    float mp = *(const float*)(pax + cl * 8);
    float lp = *(const float*)(pax + cl * 8 + 4);
    float mt = fmaxf(m_i, mp);
    float fme = fexp2(m_i - mt);
    float ltot = lsum * fme + lp * fexp2(mp - mt);
    if (h == 0 && hi == 0) {
        size_t mi = ((size_t)(cz * B_ + b) * N_ + q0 + cl) * 2;
        ML[mi] = mt;
        ML[mi + 1] = ltot;
    }
    // broadcast my wave's rescale factor per q, scale oacc
    if (hi == 0) *(float*)(mypb + cl * 4) = fme;
    float fr[16];
#pragma unroll
    for (int r = 0; r < 16; r++)
        fr[r] = *(const float*)(mypb + (((r & 3) + 8 * (r >> 2) + 4 * hi) << 2));
#pragma unroll
    for (int cb = 0; cb < 4; cb++)
#pragma unroll
        for (int r = 0; r < 16; r++) oacc[cb][r] *= fr[r];
    // exchange the partner-owned c-halves (scaled) via dead k/v region
    {
        char* myex = smem + w * 8192;
        char* paex = smem + (w ^ 1) * 8192;
        int cs = (h ^ 1) * 2;
        __syncthreads();
        *(f32x16*)(myex + l * 128)      = oacc[cs];
        *(f32x16*)(myex + l * 128 + 64) = oacc[cs + 1];
        __syncthreads();
        f32x16 o0 = *(const f32x16*)(paex + l * 128);
        f32x16 o1 = *(const f32x16*)(paex + l * 128 + 64);
        oacc[2 * h]     += o0;
        oacc[2 * h + 1] += o1;
    }
    // write my c-half of partial O
#pragma unroll
    for (int i = 0; i < 2; i++) {
        int cb = 2 * h + i;
#pragma unroll
        for (int r = 0; r < 16; r++) {
            int q = q0 + (r & 3) + 8 * (r >> 2) + 4 * hi;
            OP[((size_t)(cz * B_ + b) * N_ + q) * CI_ + cb * 32 + cl] =
                __float2bfloat16(oacc[cb][r]);
        }
    }
}

// ------- fused epilogue v2 (frozen from R13) -------------------------------
template <int NC>
__global__ __launch_bounds__(256) void out_fused2(const float* x, char* ws, float* y,
                                                  unsigned long long off_part,
                                                  unsigned long long off_ml) {
    const __hip_bfloat16* OP = (const __hip_bfloat16*)(ws + off_part);
    const float* ML = (const float*)(ws + off_ml);
    const __hip_bfloat16* Wo = (const __hip_bfloat16*)(ws + OFF_WOUT);
    const float* Bout = (const float*)(ws + OFF_BOUT);

    __shared__ char oT[16 * 256];

    int b = blockIdx.y;
    int n0 = blockIdx.x * 16;
    int t = threadIdx.x;

    {
        int nl = t >> 4;
        int cg = t & 15;
        int n = n0 + nl;
        float mz[NC], lz[NC], M = -1e30f;
#pragma unroll
        for (int z = 0; z < NC; z++) {
            size_t mi = ((size_t)(z * B_ + b) * N_ + n) * 2;
            mz[z] = ML[mi]; lz[z] = ML[mi + 1];
            M = fmaxf(M, mz[z]);
        }
        float Ls = 0.f, wz[NC];
#pragma unroll
        for (int z = 0; z < NC; z++) { wz[z] = fexp2(mz[z] - M); Ls += lz[z] * wz[z]; }
        float inv = 1.f / Ls;
        float o8[8] = {};
#pragma unroll
        for (int z = 0; z < NC; z++) {
            s16x8 v = ld8(OP + ((size_t)(z * B_ + b) * N_ + n) * CI_ + cg * 8);
            float wv = wz[z] * inv;
#pragma unroll
            for (int e = 0; e < 8; e++) o8[e] += wv * b2f(v[e]);
        }
        union { unsigned int u[4]; s16x8 v; } r;
#pragma unroll
        for (int e = 0; e < 4; e++) r.u[e] = pk2(o8[2 * e], o8[2 * e + 1]);
        *(s16x8*)(&oT[nl * 256 + ((cg ^ (nl & 7)) << 4)]) = r.v;
    }
    __syncthreads();

    int w = t >> 6, l = t & 63, lr = l & 15, lg = l >> 4;
    int o0 = w * 64;
    f32x4 acc[4] = {};
#pragma unroll
    for (int kk = 0; kk < 4; kk++) {
        int slot = kk * 4 + lg;
        s16x8 bb = *(const s16x8*)(&oT[lr * 256 + ((slot ^ (lr & 7)) << 4)]);
#pragma unroll
        for (int of = 0; of < 4; of++) {
            s16x8 a = ld8(Wo + (size_t)(o0 + 16 * of + lr) * CI_ + kk * 32 + lg * 8);
            acc[of] = mfma16(a, bb, acc[of]);
        }
    }
#pragma unroll
    for (int of = 0; of < 4; of++) {
#pragma unroll
        for (int i = 0; i < 4; i++) {
            int o = o0 + 16 * of + lg * 4 + i;
            int n = n0 + lr;
            size_t idx = (size_t)(b * C_ + o) * N_ + n;
            y[idx] = acc[of][i] + Bout[o] + x[idx];
        }
    }
}

extern "C" void kernel_launch(void* const* d_in, const int* in_sizes, int n_in,
                              void* d_out, int out_size, void* d_ws, size_t ws_size,
                              hipStream_t stream) {
    const float* x  = (const float*)d_in[0];
    const float* wg = (const float*)d_in[1];
    const float* bg = (const float*)d_in[2];
    const float* wt = (const float*)d_in[3];
    const float* bt = (const float*)d_in[4];
    const float* wp = (const float*)d_in[5];
    const float* bp = (const float*)d_in[6];
    const float* wo = (const float*)d_in[7];
    const float* bo = (const float*)d_in[8];
    char* ws = (char*)d_ws;
    float* y = (float*)d_out;

    // nchunk=4: 64qt * 4b * 4 = 1024 flash blocks = exactly 4/CU, no tail
    unsigned long long need4 = OFF_END + (16ull << 20) + (1ull << 20);
    int nchunk;
    unsigned long long off_part, off_ml;
    if (ws_size >= need4) {
        nchunk = 4; off_part = OFF_END; off_ml = OFF_END + (16ull << 20);
    } else {
        nchunk = 2; off_part = 0ull; off_ml = OFF_END;
    }

    prep_weights<<<256, 256, 0, stream>>>(wg, bg, wt, bt, wp, bp, wo, bo, ws);
    proj<<<dim3(128, 4), 256, 0, stream>>>(x, ws);
    flash12<<<dim3(64 * B_ * nchunk), 256, 0, stream>>>(ws, nchunk, off_part, off_ml);
    if (nchunk == 4)
        out_fused2<4><<<dim3(256, 4), 256, 0, stream>>>(x, ws, y, off_part, off_ml);
    else
        out_fused2<2><<<dim3(256, 4), 256, 0, stream>>>(x, ws, y, off_part, off_ml);
}

// Round 16
// 94.782 us; speedup vs baseline: 7.1789x; 7.1789x over previous
//
#include <hip/hip_runtime.h>
#include <hip/hip_bf16.h>

// NonLocal block == flash attention (4 heads, N=4096, D=128) + 1x1-conv GEMMs.
// Round 16: best-known configuration restored. proj (R12 vectorized) +
// flash9 (best of 8 flash variants, 50.2us) + combine + gemm_out (R12,
// support 44.4us). No new experiments.

typedef float f32x4 __attribute__((ext_vector_type(4)));
typedef float f32x16 __attribute__((ext_vector_type(16)));
typedef short s16x8 __attribute__((ext_vector_type(8)));
typedef short s16x4 __attribute__((ext_vector_type(4)));

#define B_  4
#define C_  256
#define CI_ 128
#define N_  4096

// workspace layout (bytes)
#define OFF_Q    (8ull  << 20)           // bf16 [B][N][CI]  4 MB (theta^T, scaled)
#define OFF_K    (12ull << 20)           // bf16 [B][N][CI]  4 MB (phi^T)
#define OFF_G    (16ull << 20)           // bf16 [B][CI][N]  4 MB (g, V^T layout)
#define OFF_O    (20ull << 20)           // bf16 [B][N][CI]  4 MB (combined attn out)
#define OFF_WQK  (24ull << 20)
#define OFF_WG   (OFF_WQK + 131072)
#define OFF_WOUT (OFF_WG  + 65536)
#define OFF_BQK  (OFF_WOUT + 65536)
#define OFF_BG   (OFF_BQK + 1024)
#define OFF_BOUT (OFF_BG  + 512)
#define OFF_END  (OFF_BOUT + 1024)       // = 25430528

__device__ inline f32x4 mfma16(s16x8 a, s16x8 b, f32x4 c) {
    return __builtin_amdgcn_mfma_f32_16x16x32_bf16(a, b, c, 0, 0, 0);
}
__device__ inline f32x16 mfma32(s16x8 a, s16x8 b, f32x16 c) {
    return __builtin_amdgcn_mfma_f32_32x32x16_bf16(a, b, c, 0, 0, 0);
}
__device__ inline s16x8 ld8(const __hip_bfloat16* p) { return *(const s16x8*)p; }
__device__ inline float b2f(short u) {
    return __uint_as_float(((unsigned int)(unsigned short)u) << 16);
}
__device__ inline unsigned int pk2(float a, float b) {
    __hip_bfloat162 h;
    h.x = __float2bfloat16(a); h.y = __float2bfloat16(b);
    return *(unsigned int*)&h;
}
__device__ inline void gload_lds16(const void* g, void* l) {
    __builtin_amdgcn_global_load_lds(
        (const __attribute__((address_space(1))) unsigned int*)g,
        (__attribute__((address_space(3))) unsigned int*)l, 16, 0, 0);
}
__device__ inline float fexp2(float x) { return __builtin_amdgcn_exp2f(x); }

// ---------------- weight prep: fp32 -> bf16; fold log2e/sqrt(Ci) into theta
__global__ void prep_weights(const float* wg, const float* bg,
                             const float* wt, const float* bt,
                             const float* wp, const float* bp,
                             const float* wo, const float* bo, char* ws) {
    __hip_bfloat16* Wqk  = (__hip_bfloat16*)(ws + OFF_WQK);
    __hip_bfloat16* Wg   = (__hip_bfloat16*)(ws + OFF_WG);
    __hip_bfloat16* Wout = (__hip_bfloat16*)(ws + OFF_WOUT);
    float* Bqk  = (float*)(ws + OFF_BQK);
    float* Bg   = (float*)(ws + OFF_BG);
    float* Bout = (float*)(ws + OFF_BOUT);
    const float rs = 0.08838834764831845f * 1.4426950408889634f;  // 1/sqrt(128)*log2(e)
    int idx = blockIdx.x * 256 + threadIdx.x;
    if (idx < 65536) {
        int r = idx >> 8, c = idx & 255;
        float v = (r < 128) ? wt[r * 256 + c] * rs : wp[(r - 128) * 256 + c];
        Wqk[idx] = __float2bfloat16(v);
    }
    if (idx < 32768) {
        Wg[idx]   = __float2bfloat16(wg[idx]);
        Wout[idx] = __float2bfloat16(wo[idx]);
    }
    if (idx < 256) { Bqk[idx] = (idx < 128) ? bt[idx] * rs : bp[idx - 128]; Bout[idx] = bo[idx]; }
    if (idx < 128) Bg[idx] = bg[idx];
}

// ---------------- fused transpose + projection (R12, vectorized staging) ---
__global__ __launch_bounds__(256) void proj(const float* x, char* ws) {
    const __hip_bfloat16* Wqk = (const __hip_bfloat16*)(ws + OFF_WQK);
    const __hip_bfloat16* Wg  = (const __hip_bfloat16*)(ws + OFF_WG);
    const float* Bqk = (const float*)(ws + OFF_BQK);
    const float* Bg  = (const float*)(ws + OFF_BG);
    __hip_bfloat16* Q  = (__hip_bfloat16*)(ws + OFF_Q);
    __hip_bfloat16* Kb = (__hip_bfloat16*)(ws + OFF_K);
    __hip_bfloat16* G  = (__hip_bfloat16*)(ws + OFF_G);

    __shared__ char at[32 * 512];   // [32 n][256 c] bf16, 16B slots XOR-swizzled

    int b = blockIdx.y, n0 = blockIdx.x * 32;
    int t = threadIdx.x;
    int w = t >> 6, l = t & 63, lr = l & 15, lg = l >> 4;

    {
        int n4 = (t & 7) * 4;              // n offset within tile
        int cp = t >> 3;                   // 0..31 c-pair base index
        const float* xb = x + ((size_t)b * C_) * N_ + n0 + n4;
#pragma unroll
        for (int p = 0; p < 4; p++) {
            int c0 = (p * 32 + cp) * 2;
            f32x4 vA = *(const f32x4*)(xb + (size_t)c0 * N_);
            f32x4 vB = *(const f32x4*)(xb + (size_t)(c0 + 1) * N_);
            int slot = c0 >> 3, coff = (c0 & 7) << 1;
#pragma unroll
            for (int i = 0; i < 4; i++) {
                int n = n4 + i;
                *(unsigned int*)(&at[n * 512 + ((slot ^ (n & 7)) << 4) + coff]) =
                    pk2(vA[i], vB[i]);
            }
        }
    }
    __syncthreads();

    f32x4 acc[4][2] = {};    // QK path: [of][nf]
    f32x4 accg[2][2] = {};   // G  path: [og][nf]
    int o0q = w * 64, o0g = w * 32;
#pragma unroll
    for (int kk = 0; kk < 8; kk++) {
        s16x8 a[2];
#pragma unroll
        for (int nf = 0; nf < 2; nf++) {
            int row = nf * 16 + lr;
            int s = (4 * kk + lg) ^ (row & 7);
            a[nf] = *(const s16x8*)(&at[row * 512 + s * 16]);
        }
#pragma unroll
        for (int of = 0; of < 4; of++) {
            s16x8 bb = ld8(Wqk + (size_t)(o0q + 16 * of + lr) * C_ + kk * 32 + lg * 8);
            acc[of][0] = mfma16(a[0], bb, acc[of][0]);
            acc[of][1] = mfma16(a[1], bb, acc[of][1]);
        }
#pragma unroll
        for (int og = 0; og < 2; og++) {
            s16x8 ag = ld8(Wg + (size_t)(o0g + 16 * og + lr) * C_ + kk * 32 + lg * 8);
            accg[og][0] = mfma16(ag, a[0], accg[og][0]);
            accg[og][1] = mfma16(ag, a[1], accg[og][1]);
        }
    }
#pragma unroll
    for (int of = 0; of < 4; of++) {
        int o = o0q + 16 * of + lr;
        float bias = Bqk[o];
#pragma unroll
        for (int nf = 0; nf < 2; nf++) {
#pragma unroll
            for (int i = 0; i < 4; i++) {
                int n = n0 + 16 * nf + lg * 4 + i;
                float v = acc[of][nf][i] + bias;
                if (o < 128) Q [(size_t)(b * N_ + n) * CI_ + o]         = __float2bfloat16(v);
                else         Kb[(size_t)(b * N_ + n) * CI_ + (o - 128)] = __float2bfloat16(v);
            }
        }
    }
#pragma unroll
    for (int og = 0; og < 2; og++) {
#pragma unroll
        for (int i = 0; i < 4; i++) {
            int o = o0g + 16 * og + lg * 4 + i;
            float bias = Bg[o];
#pragma unroll
            for (int nf = 0; nf < 2; nf++) {
                int n = n0 + 16 * nf + lr;
                G[(size_t)(b * CI_ + o) * N_ + n] = __float2bfloat16(accg[og][nf][i] + bias);
            }
        }
    }
}

// ---------------- flash v9: 32x32x16, in-register P (frozen, best variant) -
__global__ __launch_bounds__(256, 3) void flash9(char* ws, int nchunk,
                                                 unsigned long long off_part,
                                                 unsigned long long off_ml) {
    const __hip_bfloat16* Q  = (const __hip_bfloat16*)(ws + OFF_Q);
    const __hip_bfloat16* Kb = (const __hip_bfloat16*)(ws + OFF_K);
    const __hip_bfloat16* G  = (const __hip_bfloat16*)(ws + OFF_G);
    __hip_bfloat16* OP = (__hip_bfloat16*)(ws + off_part);
    float* ML = (float*)(ws + off_ml);

    __shared__ char kbuf[2][32 * 256];   // K tile [32 j][256 B], slot key (row&7)
    __shared__ char vbuf[2][128 * 64];   // V tile [128 c][64 B], slot key ((c>>1)&3)

    int L = blockIdx.x;
    int npairs = B_ * nchunk;
    int pair = L % npairs, qt = L / npairs;
    int b = pair / nchunk, cz = pair % nchunk;
    int per = 128 / nchunk, rem = 128 % nchunk;
    int jb_t = per * cz + (cz < rem ? cz : rem);
    int sz_t = per + (cz < rem ? 1 : 0);
    int jb = jb_t << 5, je = jb + (sz_t << 5);

    int w = threadIdx.x >> 6, l = threadIdx.x & 63;
    int cl = l & 31, hi = l >> 5;
    int q0 = qt * 128 + w * 32;
    int kkey = (l & 7) << 4;        // K slot key (row = cl)
    int vkey = (l >> 1) & 3;        // V slot key (row c = cb*32+cl)

    auto STAGE = [&](int pb_, int j0_) {
#pragma unroll
        for (int i = 0; i < 2; i++) {
            int row = w * 8 + i * 4 + (l >> 4);
            int bcol = ((l & 15) << 4) ^ ((row & 7) << 4);
            const char* src = (const char*)Kb + (((size_t)b * N_ + j0_ + row) << 8) + bcol;
            gload_lds16(src, &kbuf[pb_][(w * 8 + i * 4) * 256]);
        }
#pragma unroll
        for (int i = 0; i < 2; i++) {
            int c = w * 32 + i * 16 + (l >> 2);
            int srcslot = (l & 3) ^ ((l >> 3) & 3);
            const char* src = (const char*)G + ((((size_t)b * CI_ + c) * N_ + j0_) << 1)
                              + (srcslot << 4);
            gload_lds16(src, &vbuf[pb_][(w * 32 + i * 16) * 64]);
        }
    };

    // Q as B-operand (32x32x16): lane holds Q[k = st*16 + hi*8 + e][q = q0+cl]
    s16x8 qb[8];
    {
        const __hip_bfloat16* qrow = Q + ((size_t)b * N_ + q0 + cl) * CI_ + hi * 8;
#pragma unroll
        for (int st = 0; st < 8; st++) qb[st] = ld8(qrow + st * 16);
    }

    f32x16 oacc[4] = {};
    float m_i = 0.f, lsum = 0.f;

    STAGE(0, jb);
    __syncthreads();
    int pb = 0;

    for (int j0 = jb; j0 < je; j0 += 32) {
        if (j0 + 32 < je) STAGE(pb ^ 1, j0 + 32);
        const char* kb = kbuf[pb];
        const char* vbb = vbuf[pb];
        f32x16 s = {};
        __builtin_amdgcn_s_setprio(1);
#pragma unroll
        for (int st = 0; st < 8; st++) {
            s16x8 kf = *(const s16x8*)(kb + cl * 256 + ((((st << 1) + hi) << 4) ^ kkey));
            s = mfma32(kf, qb[st], s);
        }
        __builtin_amdgcn_s_setprio(0);
        if (j0 == jb) {
            float t0 = fmaxf(fmaxf(s[0], s[1]), fmaxf(s[2], s[3]));
            float t1 = fmaxf(fmaxf(s[4], s[5]), fmaxf(s[6], s[7]));
            float t2 = fmaxf(fmaxf(s[8], s[9]), fmaxf(s[10], s[11]));
            float t3 = fmaxf(fmaxf(s[12], s[13]), fmaxf(s[14], s[15]));
            float tm = fmaxf(fmaxf(t0, t1), fmaxf(t2, t3));
            tm = fmaxf(tm, __shfl_xor(tm, 32));
            m_i = tm;
        }
#pragma unroll
        for (int r = 0; r < 16; r++) s[r] = fexp2(s[r] - m_i);
        lsum += ((s[0] + s[1]) + (s[2] + s[3])) + ((s[4] + s[5]) + (s[6] + s[7]))
              + ((s[8] + s[9]) + (s[10] + s[11])) + ((s[12] + s[13]) + (s[14] + s[15]));
        union { unsigned int u[4]; s16x8 v; } pa0, pa1;
#pragma unroll
        for (int i = 0; i < 4; i++) {
            pa0.u[i] = pk2(s[2 * i], s[2 * i + 1]);
            pa1.u[i] = pk2(s[8 + 2 * i], s[9 + 2 * i]);
        }
        __builtin_amdgcn_s_setprio(1);
#pragma unroll
        for (int u = 0; u < 2; u++) {
            s16x8 pa = u ? pa1.v : pa0.v;
#pragma unroll
            for (int cb = 0; cb < 4; cb++) {
                const char* base = vbb + ((cb * 32 + cl) << 6) + hi * 8;
                union { s16x4 h[2]; s16x8 v; } vf;
                vf.h[0] = *(const s16x4*)(base + ((((u << 1))     ^ vkey) << 4));
                vf.h[1] = *(const s16x4*)(base + ((((u << 1) | 1) ^ vkey) << 4));
                oacc[cb] = mfma32(pa, vf.v, oacc[cb]);
            }
        }
        __builtin_amdgcn_s_setprio(0);
        __syncthreads();
        pb ^= 1;
    }
    lsum += __shfl_xor(lsum, 32);
#pragma unroll
    for (int cb = 0; cb < 4; cb++) {
#pragma unroll
        for (int r = 0; r < 16; r++) {
            int q = q0 + (r & 3) + 8 * (r >> 2) + 4 * hi;
            OP[((size_t)(cz * B_ + b) * N_ + q) * CI_ + cb * 32 + cl] =
                __float2bfloat16(oacc[cb][r]);
        }
    }
    if (l < 32) {
        size_t mi = ((size_t)(cz * B_ + b) * N_ + q0 + l) * 2;
        ML[mi] = m_i;
        ML[mi + 1] = lsum;
    }
}

// ---------------- combine split-KV partials -> O (frozen) ------------------
template <int NC>
__global__ __launch_bounds__(256) void combine(char* ws,
                                               unsigned long long off_part,
                                               unsigned long long off_ml) {
    const __hip_bfloat16* OP = (const __hip_bfloat16*)(ws + off_part);
    const float* ML = (const float*)(ws + off_ml);
    __hip_bfloat16* O = (__hip_bfloat16*)(ws + OFF_O);
    int idx = blockIdx.x * 256 + threadIdx.x;      // B*N*16 threads
    int cg = idx & 15, n = (idx >> 4) & (N_ - 1), b = idx >> 16;
    float mz[NC], lz[NC], M = -1e30f;
#pragma unroll
    for (int z = 0; z < NC; z++) {
        size_t mi = ((size_t)(z * B_ + b) * N_ + n) * 2;
        mz[z] = ML[mi]; lz[z] = ML[mi + 1];
        M = fmaxf(M, mz[z]);
    }
    float Lsum = 0.f, wz[NC];
#pragma unroll
    for (int z = 0; z < NC; z++) { wz[z] = fexp2(mz[z] - M); Lsum += lz[z] * wz[z]; }
    float inv = 1.f / Lsum;
    float o[8] = {};
#pragma unroll
    for (int z = 0; z < NC; z++) {
        s16x8 v = ld8(OP + ((size_t)(z * B_ + b) * N_ + n) * CI_ + cg * 8);
        float wv = wz[z] * inv;
#pragma unroll
        for (int i = 0; i < 8; i++) o[i] += wv * b2f(v[i]);
    }
    s16x8 r;
#pragma unroll
    for (int i = 0; i < 8; i++) {
        __hip_bfloat16 h = __float2bfloat16(o[i]);
        r[i] = *(short*)&h;
    }
    *(s16x8*)(O + ((size_t)b * N_ + n) * CI_ + cg * 8) = r;
}

// ---------------- out projection + bias + residual (R12, 512 blocks) -------
__global__ __launch_bounds__(256) void gemm_out(const float* x, char* ws, float* y) {
    const __hip_bfloat16* Ob = (const __hip_bfloat16*)(ws + OFF_O);
    const __hip_bfloat16* Wo = (const __hip_bfloat16*)(ws + OFF_WOUT);
    const float* Bout = (const float*)(ws + OFF_BOUT);
    int b = blockIdx.y;
    int w = threadIdx.x >> 6, l = threadIdx.x & 63, lr = l & 15, lg = l >> 4;
    int n0 = blockIdx.x * 32;
    int o0 = w * 64;
    f32x4 acc[4][2] = {};   // [of][nf]
#pragma unroll
    for (int kk = 0; kk < 4; kk++) {
        s16x8 bb[2];
#pragma unroll
        for (int nf = 0; nf < 2; nf++)
            bb[nf] = ld8(Ob + (size_t)(b * N_ + n0 + 16 * nf + lr) * CI_ + kk * 32 + lg * 8);
#pragma unroll
        for (int of = 0; of < 4; of++) {
            s16x8 a = ld8(Wo + (size_t)(o0 + 16 * of + lr) * CI_ + kk * 32 + lg * 8);
#pragma unroll
            for (int nf = 0; nf < 2; nf++)
                acc[of][nf] = mfma16(a, bb[nf], acc[of][nf]);
        }
    }
#pragma unroll
    for (int of = 0; of < 4; of++) {
#pragma unroll
        for (int i = 0; i < 4; i++) {
            int o = o0 + 16 * of + lg * 4 + i;
            float bias = Bout[o];
#pragma unroll
            for (int nf = 0; nf < 2; nf++) {
                int n = n0 + 16 * nf + lr;
                size_t idx = (size_t)(b * C_ + o) * N_ + n;
                y[idx] = acc[of][nf][i] + bias + x[idx];
            }
        }
    }
}

extern "C" void kernel_launch(void* const* d_in, const int* in_sizes, int n_in,
                              void* d_out, int out_size, void* d_ws, size_t ws_size,
                              hipStream_t stream) {
    const float* x  = (const float*)d_in[0];
    const float* wg = (const float*)d_in[1];
    const float* bg = (const float*)d_in[2];
    const float* wt = (const float*)d_in[3];
    const float* bt = (const float*)d_in[4];
    const float* wp = (const float*)d_in[5];
    const float* bp = (const float*)d_in[6];
    const float* wo = (const float*)d_in[7];
    const float* bo = (const float*)d_in[8];
    char* ws = (char*)d_ws;
    float* y = (float*)d_out;

    // split-KV factor: 6 fills 256 CUs at 3 blocks/CU exactly (768 blocks)
    unsigned long long need6 = OFF_END + (24ull << 20) + (1ull << 20);
    unsigned long long need4 = OFF_END + (16ull << 20) + (1ull << 20);
    int nchunk;
    unsigned long long off_part, off_ml;
    if (ws_size >= need6) {
        nchunk = 6; off_part = OFF_END; off_ml = OFF_END + (24ull << 20);
    } else if (ws_size >= need4) {
        nchunk = 4; off_part = OFF_END; off_ml = OFF_END + (16ull << 20);
    } else {
        nchunk = 2; off_part = 0ull; off_ml = OFF_END;
    }

    prep_weights<<<256, 256, 0, stream>>>(wg, bg, wt, bt, wp, bp, wo, bo, ws);
    proj<<<dim3(128, 4), 256, 0, stream>>>(x, ws);
    flash9<<<dim3(32 * B_ * nchunk), 256, 0, stream>>>(ws, nchunk, off_part, off_ml);
    if (nchunk == 6)      combine<6><<<1024, 256, 0, stream>>>(ws, off_part, off_ml);
    else if (nchunk == 4) combine<4><<<1024, 256, 0, stream>>>(ws, off_part, off_ml);
    else                  combine<2><<<1024, 256, 0, stream>>>(ws, off_part, off_ml);
    gemm_out<<<dim3(128, 4), 256, 0, stream>>>(x, ws, y);
}

// Round 17
// 91.116 us; speedup vs baseline: 7.4677x; 1.0402x over previous
//
#include <hip/hip_runtime.h>
#include <hip/hip_bf16.h>

// NonLocal block == flash attention (4 heads, N=4096, D=128) + 1x1-conv GEMMs.
// Round 17: fp8 Q/K for the QK^T path (Q regs 32->16 => 4 waves/SIMD at
// launch_bounds(256,4), nchunk=8 => 1024 blocks = 4/CU). K stored k-major
// tiled fp8 so LDS staging is a linear DMA and reads are conflict-free.
// PV path (P, V) stays bf16 = flash9's verified layout. Support frozen.

typedef float f32x4 __attribute__((ext_vector_type(4)));
typedef float f32x16 __attribute__((ext_vector_type(16)));
typedef short s16x8 __attribute__((ext_vector_type(8)));
typedef short s16x4 __attribute__((ext_vector_type(4)));

#define B_  4
#define C_  256
#define CI_ 128
#define N_  4096

// workspace layout (bytes)
#define OFF_Q    (8ull  << 20)           // fp8 [B][N][128]   2 MB (theta^T, scaled x16*rs*log2e)
#define OFF_K    (12ull << 20)           // fp8 tiled [B][N/32][16][32][8]  2 MB
#define OFF_G    (16ull << 20)           // bf16 [B][CI][N]  4 MB (g, V^T layout)
#define OFF_O    (20ull << 20)           // bf16 [B][N][CI]  4 MB (combined attn out)
#define OFF_WQK  (24ull << 20)
#define OFF_WG   (OFF_WQK + 131072)
#define OFF_WOUT (OFF_WG  + 65536)
#define OFF_BQK  (OFF_WOUT + 65536)
#define OFF_BG   (OFF_BQK + 1024)
#define OFF_BOUT (OFF_BG  + 512)
#define OFF_END  (OFF_BOUT + 1024)       // = 25430528

__device__ inline f32x4 mfma16(s16x8 a, s16x8 b, f32x4 c) {
    return __builtin_amdgcn_mfma_f32_16x16x32_bf16(a, b, c, 0, 0, 0);
}
__device__ inline f32x16 mfma32(s16x8 a, s16x8 b, f32x16 c) {
    return __builtin_amdgcn_mfma_f32_32x32x16_bf16(a, b, c, 0, 0, 0);
}
__device__ inline f32x16 mfma32f8(long a, long b, f32x16 c) {
    return __builtin_amdgcn_mfma_f32_32x32x16_fp8_fp8(a, b, c, 0, 0, 0);
}
__device__ inline s16x8 ld8(const __hip_bfloat16* p) { return *(const s16x8*)p; }
__device__ inline float b2f(short u) {
    return __uint_as_float(((unsigned int)(unsigned short)u) << 16);
}
__device__ inline unsigned int pk2(float a, float b) {
    __hip_bfloat162 h;
    h.x = __float2bfloat16(a); h.y = __float2bfloat16(b);
    return *(unsigned int*)&h;
}
__device__ inline unsigned char f2fp8(float v) {
    int r = __builtin_amdgcn_cvt_pk_fp8_f32(v, v, 0, false);
    return (unsigned char)(r & 0xff);
}
__device__ inline void gload_lds16(const void* g, void* l) {
    __builtin_amdgcn_global_load_lds(
        (const __attribute__((address_space(1))) unsigned int*)g,
        (__attribute__((address_space(3))) unsigned int*)l, 16, 0, 0);
}
__device__ inline float fexp2(float x) { return __builtin_amdgcn_exp2f(x); }

// ---------------- weight prep: theta scaled by 16*rs*log2e (fp8 headroom) --
__global__ void prep_weights(const float* wg, const float* bg,
                             const float* wt, const float* bt,
                             const float* wp, const float* bp,
                             const float* wo, const float* bo, char* ws) {
    __hip_bfloat16* Wqk  = (__hip_bfloat16*)(ws + OFF_WQK);
    __hip_bfloat16* Wg   = (__hip_bfloat16*)(ws + OFF_WG);
    __hip_bfloat16* Wout = (__hip_bfloat16*)(ws + OFF_WOUT);
    float* Bqk  = (float*)(ws + OFF_BQK);
    float* Bg   = (float*)(ws + OFF_BG);
    float* Bout = (float*)(ws + OFF_BOUT);
    const float rs16 = 0.08838834764831845f * 1.4426950408889634f * 16.0f;
    int idx = blockIdx.x * 256 + threadIdx.x;
    if (idx < 65536) {
        int r = idx >> 8, c = idx & 255;
        float v = (r < 128) ? wt[r * 256 + c] * rs16 : wp[(r - 128) * 256 + c];
        Wqk[idx] = __float2bfloat16(v);
    }
    if (idx < 32768) {
        Wg[idx]   = __float2bfloat16(wg[idx]);
        Wout[idx] = __float2bfloat16(wo[idx]);
    }
    if (idx < 256) { Bqk[idx] = (idx < 128) ? bt[idx] * rs16 : bp[idx - 128]; Bout[idx] = bo[idx]; }
    if (idx < 128) Bg[idx] = bg[idx];
}

// ---------------- fused transpose + projection; Q/K written as fp8 ---------
__global__ __launch_bounds__(256) void proj(const float* x, char* ws) {
    const __hip_bfloat16* Wqk = (const __hip_bfloat16*)(ws + OFF_WQK);
    const __hip_bfloat16* Wg  = (const __hip_bfloat16*)(ws + OFF_WG);
    const float* Bqk = (const float*)(ws + OFF_BQK);
    const float* Bg  = (const float*)(ws + OFF_BG);
    unsigned char* Qf = (unsigned char*)(ws + OFF_Q);
    unsigned char* Kt = (unsigned char*)(ws + OFF_K);
    __hip_bfloat16* G = (__hip_bfloat16*)(ws + OFF_G);

    __shared__ char at[32 * 512];   // [32 n][256 c] bf16, 16B slots XOR-swizzled

    int b = blockIdx.y, n0 = blockIdx.x * 32;
    int t = threadIdx.x;
    int w = t >> 6, l = t & 63, lr = l & 15, lg = l >> 4;

    {
        int n4 = (t & 7) * 4;
        int cp = t >> 3;
        const float* xb = x + ((size_t)b * C_) * N_ + n0 + n4;
#pragma unroll
        for (int p = 0; p < 4; p++) {
            int c0 = (p * 32 + cp) * 2;
            f32x4 vA = *(const f32x4*)(xb + (size_t)c0 * N_);
            f32x4 vB = *(const f32x4*)(xb + (size_t)(c0 + 1) * N_);
            int slot = c0 >> 3, coff = (c0 & 7) << 1;
#pragma unroll
            for (int i = 0; i < 4; i++) {
                int n = n4 + i;
                *(unsigned int*)(&at[n * 512 + ((slot ^ (n & 7)) << 4) + coff]) =
                    pk2(vA[i], vB[i]);
            }
        }
    }
    __syncthreads();

    f32x4 acc[4][2] = {};    // QK path: [of][nf]
    f32x4 accg[2][2] = {};   // G  path: [og][nf]
    int o0q = w * 64, o0g = w * 32;
#pragma unroll
    for (int kk = 0; kk < 8; kk++) {
        s16x8 a[2];
#pragma unroll
        for (int nf = 0; nf < 2; nf++) {
            int row = nf * 16 + lr;
            int s = (4 * kk + lg) ^ (row & 7);
            a[nf] = *(const s16x8*)(&at[row * 512 + s * 16]);
        }
#pragma unroll
        for (int of = 0; of < 4; of++) {
            s16x8 bb = ld8(Wqk + (size_t)(o0q + 16 * of + lr) * C_ + kk * 32 + lg * 8);
            acc[of][0] = mfma16(a[0], bb, acc[of][0]);
            acc[of][1] = mfma16(a[1], bb, acc[of][1]);
        }
#pragma unroll
        for (int og = 0; og < 2; og++) {
            s16x8 ag = ld8(Wg + (size_t)(o0g + 16 * og + lr) * C_ + kk * 32 + lg * 8);
            accg[og][0] = mfma16(ag, a[0], accg[og][0]);
            accg[og][1] = mfma16(ag, a[1], accg[og][1]);
        }
    }
    // QK epilogue -> fp8. Q: [b][n][o] (o<128). K: tiled [b][n>>5][k8][n&31][e]
#pragma unroll
    for (int of = 0; of < 4; of++) {
        int o = o0q + 16 * of + lr;
        float bias = Bqk[o];
#pragma unroll
        for (int nf = 0; nf < 2; nf++) {
#pragma unroll
            for (int i = 0; i < 4; i++) {
                int n = n0 + 16 * nf + lg * 4 + i;
                float v = acc[of][nf][i] + bias;
                unsigned char u8 = f2fp8(v);
                if (o < 128) {
                    Qf[((size_t)b * N_ + n) * 128 + o] = u8;
                } else {
                    int op = o - 128;
                    size_t a2 = (((size_t)b * (N_ / 32) + (n >> 5)) << 12) +
                                ((op >> 3) << 8) + ((n & 31) << 3) + (op & 7);
                    Kt[a2] = u8;
                }
            }
        }
    }
#pragma unroll
    for (int og = 0; og < 2; og++) {
#pragma unroll
        for (int i = 0; i < 4; i++) {
            int o = o0g + 16 * og + lg * 4 + i;
            float bias = Bg[o];
#pragma unroll
            for (int nf = 0; nf < 2; nf++) {
                int n = n0 + 16 * nf + lr;
                G[(size_t)(b * CI_ + o) * N_ + n] = __float2bfloat16(accg[og][nf][i] + bias);
            }
        }
    }
}

// ---------------- flash fp8-QK: 32x32x16 fp8 QK + bf16 PV, 4 waves/SIMD ----
// grid: 32 qt * B_ * nchunk blocks of 256 (4 waves); wave = 32 q, KVBLK=32.
__global__ __launch_bounds__(256, 4) void flashf8(char* ws, int nchunk,
                                                  unsigned long long off_part,
                                                  unsigned long long off_ml) {
    const unsigned char* Qf = (const unsigned char*)(ws + OFF_Q);
    const unsigned char* Kt = (const unsigned char*)(ws + OFF_K);
    const __hip_bfloat16* G = (const __hip_bfloat16*)(ws + OFF_G);
    __hip_bfloat16* OP = (__hip_bfloat16*)(ws + off_part);
    float* ML = (float*)(ws + off_ml);

    __shared__ char kbuf[2][4096];       // K tile k-major [16 k8][32 j][8], linear
    __shared__ char vbuf[2][128 * 64];   // V tile [128 c][64 B], slot key ((c>>1)&3)

    int L = blockIdx.x;
    int npairs = B_ * nchunk;
    int pair = L % npairs, qt = L / npairs;
    int b = pair / nchunk, cz = pair % nchunk;
    int per = 128 / nchunk, rem = 128 % nchunk;
    int jb_t = per * cz + (cz < rem ? cz : rem);
    int sz_t = per + (cz < rem ? 1 : 0);
    int jb = jb_t << 5, je = jb + (sz_t << 5);

    int w = threadIdx.x >> 6, l = threadIdx.x & 63;
    int cl = l & 31, hi = l >> 5;
    int q0 = qt * 128 + w * 32;
    int vkey = (l >> 1) & 3;        // V slot key (row c = cb*32+cl)

    auto STAGE = [&](int pb_, int j0_) {
        // K: linear 4 KB copy from tiled global (1 DMA op per wave)
        {
            const char* src = (const char*)Kt +
                (((size_t)b * (N_ / 32) + (j0_ >> 5)) << 12) + w * 1024 + (l << 4);
            gload_lds16(src, &kbuf[pb_][w * 1024]);
        }
#pragma unroll
        for (int i = 0; i < 2; i++) {
            int c = w * 32 + i * 16 + (l >> 2);
            int srcslot = (l & 3) ^ ((l >> 3) & 3);
            const char* src = (const char*)G + ((((size_t)b * CI_ + c) * N_ + j0_) << 1)
                              + (srcslot << 4);
            gload_lds16(src, &vbuf[pb_][(w * 32 + i * 16) * 64]);
        }
    };

    // Q fp8 as B-operand: lane holds Q[k = st*16 + hi*8 + e][q = q0+cl]
    long qf[8];
    {
        const char* qrow = (const char*)Qf + ((size_t)b * N_ + q0 + cl) * 128 + hi * 8;
#pragma unroll
        for (int st = 0; st < 8; st++) qf[st] = *(const long*)(qrow + st * 16);
    }

    f32x16 oacc[4] = {};
    float m_i = 0.f, lsum = 0.f, negmc = 0.f;

    STAGE(0, jb);
    __syncthreads();
    int pb = 0;

    for (int j0 = jb; j0 < je; j0 += 32) {
        if (j0 + 32 < je) STAGE(pb ^ 1, j0 + 32);
        const char* kb = kbuf[pb];
        const char* vbb = vbuf[pb];
        // S^T[j][q] (x16 scale) : A = K fp8 (k-major LDS), B = Q fp8 regs
        f32x16 s = {};
        __builtin_amdgcn_s_setprio(1);
#pragma unroll
        for (int st = 0; st < 8; st++) {
            long kf = *(const long*)(kb + (((st << 1) + hi) << 8) + (cl << 3));
            s = mfma32f8(kf, qf[st], s);
        }
        __builtin_amdgcn_s_setprio(0);
        if (j0 == jb) {
            float t0 = fmaxf(fmaxf(s[0], s[1]), fmaxf(s[2], s[3]));
            float t1 = fmaxf(fmaxf(s[4], s[5]), fmaxf(s[6], s[7]));
            float t2 = fmaxf(fmaxf(s[8], s[9]), fmaxf(s[10], s[11]));
            float t3 = fmaxf(fmaxf(s[12], s[13]), fmaxf(s[14], s[15]));
            float tm = fmaxf(fmaxf(t0, t1), fmaxf(t2, t3));
            tm = fmaxf(tm, __shfl_xor(tm, 32));
            m_i = tm;
            negmc = -m_i * 0.0625f;
        }
        // p = exp2(s/16 - m/16)
#pragma unroll
        for (int r = 0; r < 16; r++) s[r] = fexp2(fmaf(s[r], 0.0625f, negmc));
        lsum += ((s[0] + s[1]) + (s[2] + s[3])) + ((s[4] + s[5]) + (s[6] + s[7]))
              + ((s[8] + s[9]) + (s[10] + s[11])) + ((s[12] + s[13]) + (s[14] + s[15]));
        union { unsigned int u[4]; s16x8 v; } pa0, pa1;
#pragma unroll
        for (int i = 0; i < 4; i++) {
            pa0.u[i] = pk2(s[2 * i], s[2 * i + 1]);
            pa1.u[i] = pk2(s[8 + 2 * i], s[9 + 2 * i]);
        }
        __builtin_amdgcn_s_setprio(1);
#pragma unroll
        for (int u = 0; u < 2; u++) {
            s16x8 pa = u ? pa1.v : pa0.v;
#pragma unroll
            for (int cb = 0; cb < 4; cb++) {
                const char* base = vbb + ((cb * 32 + cl) << 6) + hi * 8;
                union { s16x4 h[2]; s16x8 v; } vf;
                vf.h[0] = *(const s16x4*)(base + ((((u << 1))     ^ vkey) << 4));
                vf.h[1] = *(const s16x4*)(base + ((((u << 1) | 1) ^ vkey) << 4));
                oacc[cb] = mfma32(pa, vf.v, oacc[cb]);
            }
        }
        __builtin_amdgcn_s_setprio(0);
        __syncthreads();
        pb ^= 1;
    }
    lsum += __shfl_xor(lsum, 32);
#pragma unroll
    for (int cb = 0; cb < 4; cb++) {
#pragma unroll
        for (int r = 0; r < 16; r++) {
            int q = q0 + (r & 3) + 8 * (r >> 2) + 4 * hi;
            OP[((size_t)(cz * B_ + b) * N_ + q) * CI_ + cb * 32 + cl] =
                __float2bfloat16(oacc[cb][r]);
        }
    }
    if (l < 32) {
        size_t mi = ((size_t)(cz * B_ + b) * N_ + q0 + l) * 2;
        ML[mi] = m_i * 0.0625f;     // true log2 units for cross-chunk combine
        ML[mi + 1] = lsum;
    }
}

// ---------------- combine split-KV partials -> O (frozen) ------------------
template <int NC>
__global__ __launch_bounds__(256) void combine(char* ws,
                                               unsigned long long off_part,
                                               unsigned long long off_ml) {
    const __hip_bfloat16* OP = (const __hip_bfloat16*)(ws + off_part);
    const float* ML = (const float*)(ws + off_ml);
    __hip_bfloat16* O = (__hip_bfloat16*)(ws + OFF_O);
    int idx = blockIdx.x * 256 + threadIdx.x;      // B*N*16 threads
    int cg = idx & 15, n = (idx >> 4) & (N_ - 1), b = idx >> 16;
    float mz[NC], lz[NC], M = -1e30f;
#pragma unroll
    for (int z = 0; z < NC; z++) {
        size_t mi = ((size_t)(z * B_ + b) * N_ + n) * 2;
        mz[z] = ML[mi]; lz[z] = ML[mi + 1];
        M = fmaxf(M, mz[z]);
    }
    float Lsum = 0.f, wz[NC];
#pragma unroll
    for (int z = 0; z < NC; z++) { wz[z] = fexp2(mz[z] - M); Lsum += lz[z] * wz[z]; }
    float inv = 1.f / Lsum;
    float o[8] = {};
#pragma unroll
    for (int z = 0; z < NC; z++) {
        s16x8 v = ld8(OP + ((size_t)(z * B_ + b) * N_ + n) * CI_ + cg * 8);
        float wv = wz[z] * inv;
#pragma unroll
        for (int i = 0; i < 8; i++) o[i] += wv * b2f(v[i]);
    }
    s16x8 r;
#pragma unroll
    for (int i = 0; i < 8; i++) {
        __hip_bfloat16 h = __float2bfloat16(o[i]);
        r[i] = *(short*)&h;
    }
    *(s16x8*)(O + ((size_t)b * N_ + n) * CI_ + cg * 8) = r;
}

// ---------------- out projection + bias + residual (frozen from R16) -------
__global__ __launch_bounds__(256) void gemm_out(const float* x, char* ws, float* y) {
    const __hip_bfloat16* Ob = (const __hip_bfloat16*)(ws + OFF_O);
    const __hip_bfloat16* Wo = (const __hip_bfloat16*)(ws + OFF_WOUT);
    const float* Bout = (const float*)(ws + OFF_BOUT);
    int b = blockIdx.y;
    int w = threadIdx.x >> 6, l = threadIdx.x & 63, lr = l & 15, lg = l >> 4;
    int n0 = blockIdx.x * 32;
    int o0 = w * 64;
    f32x4 acc[4][2] = {};   // [of][nf]
#pragma unroll
    for (int kk = 0; kk < 4; kk++) {
        s16x8 bb[2];
#pragma unroll
        for (int nf = 0; nf < 2; nf++)
            bb[nf] = ld8(Ob + (size_t)(b * N_ + n0 + 16 * nf + lr) * CI_ + kk * 32 + lg * 8);
#pragma unroll
        for (int of = 0; of < 4; of++) {
            s16x8 a = ld8(Wo + (size_t)(o0 + 16 * of + lr) * CI_ + kk * 32 + lg * 8);
#pragma unroll
            for (int nf = 0; nf < 2; nf++)
                acc[of][nf] = mfma16(a, bb[nf], acc[of][nf]);
        }
    }
#pragma unroll
    for (int of = 0; of < 4; of++) {
#pragma unroll
        for (int i = 0; i < 4; i++) {
            int o = o0 + 16 * of + lg * 4 + i;
            float bias = Bout[o];
#pragma unroll
            for (int nf = 0; nf < 2; nf++) {
                int n = n0 + 16 * nf + lr;
                size_t idx = (size_t)(b * C_ + o) * N_ + n;
                y[idx] = acc[of][nf][i] + bias + x[idx];
            }
        }
    }
}

extern "C" void kernel_launch(void* const* d_in, const int* in_sizes, int n_in,
                              void* d_out, int out_size, void* d_ws, size_t ws_size,
                              hipStream_t stream) {
    const float* x  = (const float*)d_in[0];
    const float* wg = (const float*)d_in[1];
    const float* bg = (const float*)d_in[2];
    const float* wt = (const float*)d_in[3];
    const float* bt = (const float*)d_in[4];
    const float* wp = (const float*)d_in[5];
    const float* bp = (const float*)d_in[6];
    const float* wo = (const float*)d_in[7];
    const float* bo = (const float*)d_in[8];
    char* ws = (char*)d_ws;
    float* y = (float*)d_out;

    // split-KV factor: 8 -> 1024 flash blocks = exactly 4/CU (16 waves/CU)
    unsigned long long need8 = OFF_END + (32ull << 20) + (2ull << 20);
    unsigned long long need4 = OFF_END + (16ull << 20) + (1ull << 20);
    int nchunk;
    unsigned long long off_part, off_ml;
    if (ws_size >= need8) {
        nchunk = 8; off_part = OFF_END; off_ml = OFF_END + (32ull << 20);
    } else if (ws_size >= need4) {
        nchunk = 4; off_part = OFF_END; off_ml = OFF_END + (16ull << 20);
    } else {
        nchunk = 2; off_part = 0ull; off_ml = OFF_END;
    }

    prep_weights<<<256, 256, 0, stream>>>(wg, bg, wt, bt, wp, bp, wo, bo, ws);
    proj<<<dim3(128, 4), 256, 0, stream>>>(x, ws);
    flashf8<<<dim3(32 * B_ * nchunk), 256, 0, stream>>>(ws, nchunk, off_part, off_ml);
    if (nchunk == 8)      combine<8><<<1024, 256, 0, stream>>>(ws, off_part, off_ml);
    else if (nchunk == 4) combine<4><<<1024, 256, 0, stream>>>(ws, off_part, off_ml);
    else                  combine<2><<<1024, 256, 0, stream>>>(ws, off_part, off_ml);
    gemm_out<<<dim3(128, 4), 256, 0, stream>>>(x, ws, y);
}

// Round 18
// 85.361 us; speedup vs baseline: 7.9712x; 1.0674x over previous
//
#include <hip/hip_runtime.h>
#include <hip/hip_bf16.h>

// NonLocal block == flash attention (4 heads, N=4096, D=128) + 1x1-conv GEMMs.
// Round 18: fp8 V as well. G stored in flash-tile fp8 format Gt (linear DMA,
// conflict-free b32 reads: bank = 2c+hi); PV via mfma_f32_32x32x16_fp8_fp8;
// P packed with cvt_pk_fp8. QK path = R17 (verified). Support frozen.

typedef float f32x4 __attribute__((ext_vector_type(4)));
typedef float f32x16 __attribute__((ext_vector_type(16)));
typedef short s16x8 __attribute__((ext_vector_type(8)));

#define B_  4
#define C_  256
#define CI_ 128
#define N_  4096

// workspace layout (bytes)
#define OFF_Q    (8ull  << 20)           // fp8 [B][N][128]   2 MB (theta^T, scaled x16*rs*log2e)
#define OFF_K    (12ull << 20)           // fp8 tiled [B][N/32][16 k8][32 j][8]  2 MB
#define OFF_G    (16ull << 20)           // fp8 tiled [B][N/32][4 oct][128 c][8] 2 MB
#define OFF_O    (20ull << 20)           // bf16 [B][N][CI]  4 MB (combined attn out)
#define OFF_WQK  (24ull << 20)
#define OFF_WG   (OFF_WQK + 131072)
#define OFF_WOUT (OFF_WG  + 65536)
#define OFF_BQK  (OFF_WOUT + 65536)
#define OFF_BG   (OFF_BQK + 1024)
#define OFF_BOUT (OFF_BG  + 512)
#define OFF_END  (OFF_BOUT + 1024)       // = 25430528

__device__ inline f32x4 mfma16(s16x8 a, s16x8 b, f32x4 c) {
    return __builtin_amdgcn_mfma_f32_16x16x32_bf16(a, b, c, 0, 0, 0);
}
__device__ inline f32x16 mfma32f8(long a, long b, f32x16 c) {
    return __builtin_amdgcn_mfma_f32_32x32x16_fp8_fp8(a, b, c, 0, 0, 0);
}
__device__ inline s16x8 ld8(const __hip_bfloat16* p) { return *(const s16x8*)p; }
__device__ inline float b2f(short u) {
    return __uint_as_float(((unsigned int)(unsigned short)u) << 16);
}
__device__ inline unsigned int pk2(float a, float b) {
    __hip_bfloat162 h;
    h.x = __float2bfloat16(a); h.y = __float2bfloat16(b);
    return *(unsigned int*)&h;
}
__device__ inline unsigned char f2fp8(float v) {
    int r = __builtin_amdgcn_cvt_pk_fp8_f32(v, v, 0, false);
    return (unsigned char)(r & 0xff);
}
__device__ inline void gload_lds16(const void* g, void* l) {
    __builtin_amdgcn_global_load_lds(
        (const __attribute__((address_space(1))) unsigned int*)g,
        (__attribute__((address_space(3))) unsigned int*)l, 16, 0, 0);
}
__device__ inline float fexp2(float x) { return __builtin_amdgcn_exp2f(x); }

// ---------------- weight prep: theta scaled by 16*rs*log2e (fp8 headroom) --
__global__ void prep_weights(const float* wg, const float* bg,
                             const float* wt, const float* bt,
                             const float* wp, const float* bp,
                             const float* wo, const float* bo, char* ws) {
    __hip_bfloat16* Wqk  = (__hip_bfloat16*)(ws + OFF_WQK);
    __hip_bfloat16* Wg   = (__hip_bfloat16*)(ws + OFF_WG);
    __hip_bfloat16* Wout = (__hip_bfloat16*)(ws + OFF_WOUT);
    float* Bqk  = (float*)(ws + OFF_BQK);
    float* Bg   = (float*)(ws + OFF_BG);
    float* Bout = (float*)(ws + OFF_BOUT);
    const float rs16 = 0.08838834764831845f * 1.4426950408889634f * 16.0f;
    int idx = blockIdx.x * 256 + threadIdx.x;
    if (idx < 65536) {
        int r = idx >> 8, c = idx & 255;
        float v = (r < 128) ? wt[r * 256 + c] * rs16 : wp[(r - 128) * 256 + c];
        Wqk[idx] = __float2bfloat16(v);
    }
    if (idx < 32768) {
        Wg[idx]   = __float2bfloat16(wg[idx]);
        Wout[idx] = __float2bfloat16(wo[idx]);
    }
    if (idx < 256) { Bqk[idx] = (idx < 128) ? bt[idx] * rs16 : bp[idx - 128]; Bout[idx] = bo[idx]; }
    if (idx < 128) Bg[idx] = bg[idx];
}

// ---------------- fused transpose + projection; Q/K/G written as fp8 -------
__global__ __launch_bounds__(256) void proj(const float* x, char* ws) {
    const __hip_bfloat16* Wqk = (const __hip_bfloat16*)(ws + OFF_WQK);
    const __hip_bfloat16* Wg  = (const __hip_bfloat16*)(ws + OFF_WG);
    const float* Bqk = (const float*)(ws + OFF_BQK);
    const float* Bg  = (const float*)(ws + OFF_BG);
    unsigned char* Qf = (unsigned char*)(ws + OFF_Q);
    unsigned char* Kt = (unsigned char*)(ws + OFF_K);
    unsigned char* Gt = (unsigned char*)(ws + OFF_G);

    __shared__ char at[32 * 512];   // [32 n][256 c] bf16, 16B slots XOR-swizzled

    int b = blockIdx.y, n0 = blockIdx.x * 32;
    int t = threadIdx.x;
    int w = t >> 6, l = t & 63, lr = l & 15, lg = l >> 4;

    {
        int n4 = (t & 7) * 4;
        int cp = t >> 3;
        const float* xb = x + ((size_t)b * C_) * N_ + n0 + n4;
#pragma unroll
        for (int p = 0; p < 4; p++) {
            int c0 = (p * 32 + cp) * 2;
            f32x4 vA = *(const f32x4*)(xb + (size_t)c0 * N_);
            f32x4 vB = *(const f32x4*)(xb + (size_t)(c0 + 1) * N_);
            int slot = c0 >> 3, coff = (c0 & 7) << 1;
#pragma unroll
            for (int i = 0; i < 4; i++) {
                int n = n4 + i;
                *(unsigned int*)(&at[n * 512 + ((slot ^ (n & 7)) << 4) + coff]) =
                    pk2(vA[i], vB[i]);
            }
        }
    }
    __syncthreads();

    f32x4 acc[4][2] = {};    // QK path: [of][nf]
    f32x4 accg[2][2] = {};   // G  path: [og][nf]
    int o0q = w * 64, o0g = w * 32;
#pragma unroll
    for (int kk = 0; kk < 8; kk++) {
        s16x8 a[2];
#pragma unroll
        for (int nf = 0; nf < 2; nf++) {
            int row = nf * 16 + lr;
            int s = (4 * kk + lg) ^ (row & 7);
            a[nf] = *(const s16x8*)(&at[row * 512 + s * 16]);
        }
#pragma unroll
        for (int of = 0; of < 4; of++) {
            s16x8 bb = ld8(Wqk + (size_t)(o0q + 16 * of + lr) * C_ + kk * 32 + lg * 8);
            acc[of][0] = mfma16(a[0], bb, acc[of][0]);
            acc[of][1] = mfma16(a[1], bb, acc[of][1]);
        }
#pragma unroll
        for (int og = 0; og < 2; og++) {
            s16x8 ag = ld8(Wg + (size_t)(o0g + 16 * og + lr) * C_ + kk * 32 + lg * 8);
            accg[og][0] = mfma16(ag, a[0], accg[og][0]);
            accg[og][1] = mfma16(ag, a[1], accg[og][1]);
        }
    }
    // QK epilogue -> fp8. Q: [b][n][o]. K: tiled [b][n>>5][k8][n&31][e]
#pragma unroll
    for (int of = 0; of < 4; of++) {
        int o = o0q + 16 * of + lr;
        float bias = Bqk[o];
#pragma unroll
        for (int nf = 0; nf < 2; nf++) {
#pragma unroll
            for (int i = 0; i < 4; i++) {
                int n = n0 + 16 * nf + lg * 4 + i;
                float v = acc[of][nf][i] + bias;
                unsigned char u8 = f2fp8(v);
                if (o < 128) {
                    Qf[((size_t)b * N_ + n) * 128 + o] = u8;
                } else {
                    int op = o - 128;
                    size_t a2 = (((size_t)b * (N_ / 32) + (n >> 5)) << 12) +
                                ((op >> 3) << 8) + ((n & 31) << 3) + (op & 7);
                    Kt[a2] = u8;
                }
            }
        }
    }
    // G epilogue -> fp8 tiled: [b][n>>5][(n&31)>>3][c][n&7]
#pragma unroll
    for (int og = 0; og < 2; og++) {
#pragma unroll
        for (int i = 0; i < 4; i++) {
            int o = o0g + 16 * og + lg * 4 + i;   // c
            float bias = Bg[o];
#pragma unroll
            for (int nf = 0; nf < 2; nf++) {
                int n = n0 + 16 * nf + lr;
                float v = accg[og][nf][i] + bias;
                size_t a3 = (((size_t)b * (N_ / 32) + (n >> 5)) << 12) +
                            (((n & 31) >> 3) << 10) + (o << 3) + (n & 7);
                Gt[a3] = f2fp8(v);
            }
        }
    }
}

// ---------------- flash fp8: fp8 QK + fp8 PV, 4 waves/SIMD -----------------
// grid: 32 qt * B_ * nchunk blocks of 256 (4 waves); wave = 32 q, KVBLK=32.
__global__ __launch_bounds__(256, 4) void flashf8b(char* ws, int nchunk,
                                                   unsigned long long off_part,
                                                   unsigned long long off_ml) {
    const unsigned char* Qf = (const unsigned char*)(ws + OFF_Q);
    const unsigned char* Kt = (const unsigned char*)(ws + OFF_K);
    const unsigned char* Gt = (const unsigned char*)(ws + OFF_G);
    __hip_bfloat16* OP = (__hip_bfloat16*)(ws + off_part);
    float* ML = (float*)(ws + off_ml);

    __shared__ char kbuf[2][4096];   // K tile k-major [16 k8][32 j][8], linear
    __shared__ char vbuf[2][4096];   // V tile [4 oct][128 c][8], linear

    int L = blockIdx.x;
    int npairs = B_ * nchunk;
    int pair = L % npairs, qt = L / npairs;
    int b = pair / nchunk, cz = pair % nchunk;
    int per = 128 / nchunk, rem = 128 % nchunk;
    int jb_t = per * cz + (cz < rem ? cz : rem);
    int sz_t = per + (cz < rem ? 1 : 0);
    int jb = jb_t << 5, je = jb + (sz_t << 5);

    int w = threadIdx.x >> 6, l = threadIdx.x & 63;
    int cl = l & 31, hi = l >> 5;
    int q0 = qt * 128 + w * 32;

    auto STAGE = [&](int pb_, int j0_) {
        {
            const char* src = (const char*)Kt +
                (((size_t)b * (N_ / 32) + (j0_ >> 5)) << 12) + w * 1024 + (l << 4);
            gload_lds16(src, &kbuf[pb_][w * 1024]);
        }
        {
            const char* src = (const char*)Gt +
                (((size_t)b * (N_ / 32) + (j0_ >> 5)) << 12) + w * 1024 + (l << 4);
            gload_lds16(src, &vbuf[pb_][w * 1024]);
        }
    };

    // Q fp8 as B-operand: lane holds Q[k = st*16 + hi*8 + e][q = q0+cl]
    long qf[8];
    {
        const char* qrow = (const char*)Qf + ((size_t)b * N_ + q0 + cl) * 128 + hi * 8;
#pragma unroll
        for (int st = 0; st < 8; st++) qf[st] = *(const long*)(qrow + st * 16);
    }

    f32x16 oacc[4] = {};
    float m_i = 0.f, lsum = 0.f, negmc = 0.f;

    STAGE(0, jb);
    __syncthreads();
    int pb = 0;

    for (int j0 = jb; j0 < je; j0 += 32) {
        if (j0 + 32 < je) STAGE(pb ^ 1, j0 + 32);
        const char* kb = kbuf[pb];
        const char* vbb = vbuf[pb];
        // S^T[j][q] (x16 scale) : A = K fp8 (k-major LDS), B = Q fp8 regs
        f32x16 s = {};
        __builtin_amdgcn_s_setprio(1);
#pragma unroll
        for (int st = 0; st < 8; st++) {
            long kf = *(const long*)(kb + (((st << 1) + hi) << 8) + (cl << 3));
            s = mfma32f8(kf, qf[st], s);
        }
        __builtin_amdgcn_s_setprio(0);
        if (j0 == jb) {
            float t0 = fmaxf(fmaxf(s[0], s[1]), fmaxf(s[2], s[3]));
            float t1 = fmaxf(fmaxf(s[4], s[5]), fmaxf(s[6], s[7]));
            float t2 = fmaxf(fmaxf(s[8], s[9]), fmaxf(s[10], s[11]));
            float t3 = fmaxf(fmaxf(s[12], s[13]), fmaxf(s[14], s[15]));
            float tm = fmaxf(fmaxf(t0, t1), fmaxf(t2, t3));
            tm = fmaxf(tm, __shfl_xor(tm, 32));
            m_i = tm;
            negmc = -m_i * 0.0625f;
        }
        // p = exp2(s/16 - m/16)
#pragma unroll
        for (int r = 0; r < 16; r++) s[r] = fexp2(fmaf(s[r], 0.0625f, negmc));
        lsum += ((s[0] + s[1]) + (s[2] + s[3])) + ((s[4] + s[5]) + (s[6] + s[7]))
              + ((s[8] + s[9]) + (s[10] + s[11])) + ((s[12] + s[13]) + (s[14] + s[15]));
        // pack P -> fp8 A-frags (element order = D-reg order, pi-relabel)
        long pa01[2];
        {
            int u0 = __builtin_amdgcn_cvt_pk_fp8_f32(s[0], s[1], 0, false);
            u0     = __builtin_amdgcn_cvt_pk_fp8_f32(s[2], s[3], u0, true);
            int u1 = __builtin_amdgcn_cvt_pk_fp8_f32(s[4], s[5], 0, false);
            u1     = __builtin_amdgcn_cvt_pk_fp8_f32(s[6], s[7], u1, true);
            pa01[0] = (long)(((unsigned long long)(unsigned int)u1 << 32) |
                             (unsigned int)u0);
            int u2 = __builtin_amdgcn_cvt_pk_fp8_f32(s[8], s[9], 0, false);
            u2     = __builtin_amdgcn_cvt_pk_fp8_f32(s[10], s[11], u2, true);
            int u3 = __builtin_amdgcn_cvt_pk_fp8_f32(s[12], s[13], 0, false);
            u3     = __builtin_amdgcn_cvt_pk_fp8_f32(s[14], s[15], u3, true);
            pa01[1] = (long)(((unsigned long long)(unsigned int)u3 << 32) |
                             (unsigned int)u2);
        }
        // PV: V fp8 from LDS; element e: j = u*16 + (e&3) + 8*(e>>2) + 4*hi
        __builtin_amdgcn_s_setprio(1);
#pragma unroll
        for (int u = 0; u < 2; u++) {
            long pa = pa01[u];
#pragma unroll
            for (int cb = 0; cb < 4; cb++) {
                int c = cb * 32 + cl;
                unsigned int vlo = *(const unsigned int*)(vbb + ((u << 1) << 10) +
                                                          (c << 3) + (hi << 2));
                unsigned int vhi = *(const unsigned int*)(vbb + (((u << 1) | 1) << 10) +
                                                          (c << 3) + (hi << 2));
                long vf = (long)(((unsigned long long)vhi << 32) | vlo);
                oacc[cb] = mfma32f8(pa, vf, oacc[cb]);
            }
        }
        __builtin_amdgcn_s_setprio(0);
        __syncthreads();
        pb ^= 1;
    }
    lsum += __shfl_xor(lsum, 32);
#pragma unroll
    for (int cb = 0; cb < 4; cb++) {
#pragma unroll
        for (int r = 0; r < 16; r++) {
            int q = q0 + (r & 3) + 8 * (r >> 2) + 4 * hi;
            OP[((size_t)(cz * B_ + b) * N_ + q) * CI_ + cb * 32 + cl] =
                __float2bfloat16(oacc[cb][r]);
        }
    }
    if (l < 32) {
        size_t mi = ((size_t)(cz * B_ + b) * N_ + q0 + l) * 2;
        ML[mi] = m_i * 0.0625f;     // true log2 units for cross-chunk combine
        ML[mi + 1] = lsum;
    }
}

// ---------------- combine split-KV partials -> O (frozen) ------------------
template <int NC>
__global__ __launch_bounds__(256) void combine(char* ws,
                                               unsigned long long off_part,
                                               unsigned long long off_ml) {
    const __hip_bfloat16* OP = (const __hip_bfloat16*)(ws + off_part);
    const float* ML = (const float*)(ws + off_ml);
    __hip_bfloat16* O = (__hip_bfloat16*)(ws + OFF_O);
    int idx = blockIdx.x * 256 + threadIdx.x;      // B*N*16 threads
    int cg = idx & 15, n = (idx >> 4) & (N_ - 1), b = idx >> 16;
    float mz[NC], lz[NC], M = -1e30f;
#pragma unroll
    for (int z = 0; z < NC; z++) {
        size_t mi = ((size_t)(z * B_ + b) * N_ + n) * 2;
        mz[z] = ML[mi]; lz[z] = ML[mi + 1];
        M = fmaxf(M, mz[z]);
    }
    float Lsum = 0.f, wz[NC];
#pragma unroll
    for (int z = 0; z < NC; z++) { wz[z] = fexp2(mz[z] - M); Lsum += lz[z] * wz[z]; }
    float inv = 1.f / Lsum;
    float o[8] = {};
#pragma unroll
    for (int z = 0; z < NC; z++) {
        s16x8 v = ld8(OP + ((size_t)(z * B_ + b) * N_ + n) * CI_ + cg * 8);
        float wv = wz[z] * inv;
#pragma unroll
        for (int i = 0; i < 8; i++) o[i] += wv * b2f(v[i]);
    }
    s16x8 r;
#pragma unroll
    for (int i = 0; i < 8; i++) {
        __hip_bfloat16 h = __float2bfloat16(o[i]);
        r[i] = *(short*)&h;
    }
    *(s16x8*)(O + ((size_t)b * N_ + n) * CI_ + cg * 8) = r;
}

// ---------------- out projection + bias + residual (frozen from R16) -------
__global__ __launch_bounds__(256) void gemm_out(const float* x, char* ws, float* y) {
    const __hip_bfloat16* Ob = (const __hip_bfloat16*)(ws + OFF_O);
    const __hip_bfloat16* Wo = (const __hip_bfloat16*)(ws + OFF_WOUT);
    const float* Bout = (const float*)(ws + OFF_BOUT);
    int b = blockIdx.y;
    int w = threadIdx.x >> 6, l = threadIdx.x & 63, lr = l & 15, lg = l >> 4;
    int n0 = blockIdx.x * 32;
    int o0 = w * 64;
    f32x4 acc[4][2] = {};   // [of][nf]
#pragma unroll
    for (int kk = 0; kk < 4; kk++) {
        s16x8 bb[2];
#pragma unroll
        for (int nf = 0; nf < 2; nf++)
            bb[nf] = ld8(Ob + (size_t)(b * N_ + n0 + 16 * nf + lr) * CI_ + kk * 32 + lg * 8);
#pragma unroll
        for (int of = 0; of < 4; of++) {
            s16x8 a = ld8(Wo + (size_t)(o0 + 16 * of + lr) * CI_ + kk * 32 + lg * 8);
#pragma unroll
            for (int nf = 0; nf < 2; nf++)
                acc[of][nf] = mfma16(a, bb[nf], acc[of][nf]);
        }
    }
#pragma unroll
    for (int of = 0; of < 4; of++) {
#pragma unroll
        for (int i = 0; i < 4; i++) {
            int o = o0 + 16 * of + lg * 4 + i;
            float bias = Bout[o];
#pragma unroll
            for (int nf = 0; nf < 2; nf++) {
                int n = n0 + 16 * nf + lr;
                size_t idx = (size_t)(b * C_ + o) * N_ + n;
                y[idx] = acc[of][nf][i] + bias + x[idx];
            }
        }
    }
}

extern "C" void kernel_launch(void* const* d_in, const int* in_sizes, int n_in,
                              void* d_out, int out_size, void* d_ws, size_t ws_size,
                              hipStream_t stream) {
    const float* x  = (const float*)d_in[0];
    const float* wg = (const float*)d_in[1];
    const float* bg = (const float*)d_in[2];
    const float* wt = (const float*)d_in[3];
    const float* bt = (const float*)d_in[4];
    const float* wp = (const float*)d_in[5];
    const float* bp = (const float*)d_in[6];
    const float* wo = (const float*)d_in[7];
    const float* bo = (const float*)d_in[8];
    char* ws = (char*)d_ws;
    float* y = (float*)d_out;

    // split-KV factor: 8 -> 1024 flash blocks = exactly 4/CU (16 waves/CU)
    unsigned long long need8 = OFF_END + (32ull << 20) + (2ull << 20);
    unsigned long long need4 = OFF_END + (16ull << 20) + (1ull << 20);
    int nchunk;
    unsigned long long off_part, off_ml;
    if (ws_size >= need8) {
        nchunk = 8; off_part = OFF_END; off_ml = OFF_END + (32ull << 20);
    } else if (ws_size >= need4) {
        nchunk = 4; off_part = OFF_END; off_ml = OFF_END + (16ull << 20);
    } else {
        nchunk = 2; off_part = 0ull; off_ml = OFF_END;
    }

    prep_weights<<<256, 256, 0, stream>>>(wg, bg, wt, bt, wp, bp, wo, bo, ws);
    proj<<<dim3(128, 4), 256, 0, stream>>>(x, ws);
    flashf8b<<<dim3(32 * B_ * nchunk), 256, 0, stream>>>(ws, nchunk, off_part, off_ml);
    if (nchunk == 8)      combine<8><<<1024, 256, 0, stream>>>(ws, off_part, off_ml);
    else if (nchunk == 4) combine<4><<<1024, 256, 0, stream>>>(ws, off_part, off_ml);
    else                  combine<2><<<1024, 256, 0, stream>>>(ws, off_part, off_ml);
    gemm_out<<<dim3(128, 4), 256, 0, stream>>>(x, ws, y);
}

// Round 19
// 84.369 us; speedup vs baseline: 8.0650x; 1.0118x over previous
//
#include <hip/hip_runtime.h>
#include <hip/hip_bf16.h>
#include <hip/hip_fp16.h>

// NonLocal block == flash attention (4 heads, N=4096, D=128) + 1x1-conv GEMMs.
// Round 19: fp8 split-KV partials (flash write + combine read halve, 32->16MB
// each way). Recovery via fp16 exponent-shift trick; x4096 folded into the
// combine weight. QK/PV fp8 paths = R18 (verified). All else frozen.

typedef float f32x4 __attribute__((ext_vector_type(4)));
typedef float f32x16 __attribute__((ext_vector_type(16)));
typedef short s16x8 __attribute__((ext_vector_type(8)));

#define B_  4
#define C_  256
#define CI_ 128
#define N_  4096

// workspace layout (bytes)
#define OFF_Q    (8ull  << 20)           // fp8 [B][N][128]   2 MB (theta^T, scaled x16*rs*log2e)
#define OFF_K    (12ull << 20)           // fp8 tiled [B][N/32][16 k8][32 j][8]  2 MB
#define OFF_G    (16ull << 20)           // fp8 tiled [B][N/32][4 oct][128 c][8] 2 MB
#define OFF_O    (20ull << 20)           // bf16 [B][N][CI]  4 MB (combined attn out)
#define OFF_WQK  (24ull << 20)
#define OFF_WG   (OFF_WQK + 131072)
#define OFF_WOUT (OFF_WG  + 65536)
#define OFF_BQK  (OFF_WOUT + 65536)
#define OFF_BG   (OFF_BQK + 1024)
#define OFF_BOUT (OFF_BG  + 512)
#define OFF_END  (OFF_BOUT + 1024)       // = 25430528

__device__ inline f32x4 mfma16(s16x8 a, s16x8 b, f32x4 c) {
    return __builtin_amdgcn_mfma_f32_16x16x32_bf16(a, b, c, 0, 0, 0);
}
__device__ inline f32x16 mfma32f8(long a, long b, f32x16 c) {
    return __builtin_amdgcn_mfma_f32_32x32x16_fp8_fp8(a, b, c, 0, 0, 0);
}
__device__ inline s16x8 ld8(const __hip_bfloat16* p) { return *(const s16x8*)p; }
__device__ inline float b2f(short u) {
    return __uint_as_float(((unsigned int)(unsigned short)u) << 16);
}
__device__ inline unsigned int pk2(float a, float b) {
    __hip_bfloat162 h;
    h.x = __float2bfloat16(a); h.y = __float2bfloat16(b);
    return *(unsigned int*)&h;
}
__device__ inline unsigned char f2fp8(float v) {
    int r = __builtin_amdgcn_cvt_pk_fp8_f32(v, v, 0, false);
    return (unsigned char)(r & 0xff);
}
// fp8 e4m3 byte -> f32 * (1/256): place bits in fp16 frame (handles denormals)
__device__ inline float fp8q(unsigned int byte) {
    union { unsigned short u; __half h; } cv;
    cv.u = (unsigned short)(((byte & 0x80u) << 8) | ((byte & 0x7fu) << 7));
    return __half2float(cv.h);
}
__device__ inline void gload_lds16(const void* g, void* l) {
    __builtin_amdgcn_global_load_lds(
        (const __attribute__((address_space(1))) unsigned int*)g,
        (__attribute__((address_space(3))) unsigned int*)l, 16, 0, 0);
}
__device__ inline float fexp2(float x) { return __builtin_amdgcn_exp2f(x); }

// ---------------- weight prep: theta scaled by 16*rs*log2e (fp8 headroom) --
__global__ void prep_weights(const float* wg, const float* bg,
                             const float* wt, const float* bt,
                             const float* wp, const float* bp,
                             const float* wo, const float* bo, char* ws) {
    __hip_bfloat16* Wqk  = (__hip_bfloat16*)(ws + OFF_WQK);
    __hip_bfloat16* Wg   = (__hip_bfloat16*)(ws + OFF_WG);
    __hip_bfloat16* Wout = (__hip_bfloat16*)(ws + OFF_WOUT);
    float* Bqk  = (float*)(ws + OFF_BQK);
    float* Bg   = (float*)(ws + OFF_BG);
    float* Bout = (float*)(ws + OFF_BOUT);
    const float rs16 = 0.08838834764831845f * 1.4426950408889634f * 16.0f;
    int idx = blockIdx.x * 256 + threadIdx.x;
    if (idx < 65536) {
        int r = idx >> 8, c = idx & 255;
        float v = (r < 128) ? wt[r * 256 + c] * rs16 : wp[(r - 128) * 256 + c];
        Wqk[idx] = __float2bfloat16(v);
    }
    if (idx < 32768) {
        Wg[idx]   = __float2bfloat16(wg[idx]);
        Wout[idx] = __float2bfloat16(wo[idx]);
    }
    if (idx < 256) { Bqk[idx] = (idx < 128) ? bt[idx] * rs16 : bp[idx - 128]; Bout[idx] = bo[idx]; }
    if (idx < 128) Bg[idx] = bg[idx];
}

// ---------------- fused transpose + projection; Q/K/G written as fp8 -------
__global__ __launch_bounds__(256) void proj(const float* x, char* ws) {
    const __hip_bfloat16* Wqk = (const __hip_bfloat16*)(ws + OFF_WQK);
    const __hip_bfloat16* Wg  = (const __hip_bfloat16*)(ws + OFF_WG);
    const float* Bqk = (const float*)(ws + OFF_BQK);
    const float* Bg  = (const float*)(ws + OFF_BG);
    unsigned char* Qf = (unsigned char*)(ws + OFF_Q);
    unsigned char* Kt = (unsigned char*)(ws + OFF_K);
    unsigned char* Gt = (unsigned char*)(ws + OFF_G);

    __shared__ char at[32 * 512];   // [32 n][256 c] bf16, 16B slots XOR-swizzled

    int b = blockIdx.y, n0 = blockIdx.x * 32;
    int t = threadIdx.x;
    int w = t >> 6, l = t & 63, lr = l & 15, lg = l >> 4;

    {
        int n4 = (t & 7) * 4;
        int cp = t >> 3;
        const float* xb = x + ((size_t)b * C_) * N_ + n0 + n4;
#pragma unroll
        for (int p = 0; p < 4; p++) {
            int c0 = (p * 32 + cp) * 2;
            f32x4 vA = *(const f32x4*)(xb + (size_t)c0 * N_);
            f32x4 vB = *(const f32x4*)(xb + (size_t)(c0 + 1) * N_);
            int slot = c0 >> 3, coff = (c0 & 7) << 1;
#pragma unroll
            for (int i = 0; i < 4; i++) {
                int n = n4 + i;
                *(unsigned int*)(&at[n * 512 + ((slot ^ (n & 7)) << 4) + coff]) =
                    pk2(vA[i], vB[i]);
            }
        }
    }
    __syncthreads();

    f32x4 acc[4][2] = {};    // QK path: [of][nf]
    f32x4 accg[2][2] = {};   // G  path: [og][nf]
    int o0q = w * 64, o0g = w * 32;
#pragma unroll
    for (int kk = 0; kk < 8; kk++) {
        s16x8 a[2];
#pragma unroll
        for (int nf = 0; nf < 2; nf++) {
            int row = nf * 16 + lr;
            int s = (4 * kk + lg) ^ (row & 7);
            a[nf] = *(const s16x8*)(&at[row * 512 + s * 16]);
        }
#pragma unroll
        for (int of = 0; of < 4; of++) {
            s16x8 bb = ld8(Wqk + (size_t)(o0q + 16 * of + lr) * C_ + kk * 32 + lg * 8);
            acc[of][0] = mfma16(a[0], bb, acc[of][0]);
            acc[of][1] = mfma16(a[1], bb, acc[of][1]);
        }
#pragma unroll
        for (int og = 0; og < 2; og++) {
            s16x8 ag = ld8(Wg + (size_t)(o0g + 16 * og + lr) * C_ + kk * 32 + lg * 8);
            accg[og][0] = mfma16(ag, a[0], accg[og][0]);
            accg[og][1] = mfma16(ag, a[1], accg[og][1]);
        }
    }
    // QK epilogue -> fp8. Q: [b][n][o]. K: tiled [b][n>>5][k8][n&31][e]
#pragma unroll
    for (int of = 0; of < 4; of++) {
        int o = o0q + 16 * of + lr;
        float bias = Bqk[o];
#pragma unroll
        for (int nf = 0; nf < 2; nf++) {
#pragma unroll
            for (int i = 0; i < 4; i++) {
                int n = n0 + 16 * nf + lg * 4 + i;
                float v = acc[of][nf][i] + bias;
                unsigned char u8 = f2fp8(v);
                if (o < 128) {
                    Qf[((size_t)b * N_ + n) * 128 + o] = u8;
                } else {
                    int op = o - 128;
                    size_t a2 = (((size_t)b * (N_ / 32) + (n >> 5)) << 12) +
                                ((op >> 3) << 8) + ((n & 31) << 3) + (op & 7);
                    Kt[a2] = u8;
                }
            }
        }
    }
    // G epilogue -> fp8 tiled: [b][n>>5][(n&31)>>3][c][n&7]
#pragma unroll
    for (int og = 0; og < 2; og++) {
#pragma unroll
        for (int i = 0; i < 4; i++) {
            int o = o0g + 16 * og + lg * 4 + i;   // c
            float bias = Bg[o];
#pragma unroll
            for (int nf = 0; nf < 2; nf++) {
                int n = n0 + 16 * nf + lr;
                float v = accg[og][nf][i] + bias;
                size_t a3 = (((size_t)b * (N_ / 32) + (n >> 5)) << 12) +
                            (((n & 31) >> 3) << 10) + (o << 3) + (n & 7);
                Gt[a3] = f2fp8(v);
            }
        }
    }
}

// ---------------- flash fp8: fp8 QK + fp8 PV + fp8 partials ----------------
// grid: 32 qt * B_ * nchunk blocks of 256 (4 waves); wave = 32 q, KVBLK=32.
__global__ __launch_bounds__(256, 4) void flashf8b(char* ws, int nchunk,
                                                   unsigned long long off_part,
                                                   unsigned long long off_ml) {
    const unsigned char* Qf = (const unsigned char*)(ws + OFF_Q);
    const unsigned char* Kt = (const unsigned char*)(ws + OFF_K);
    const unsigned char* Gt = (const unsigned char*)(ws + OFF_G);
    unsigned char* OP = (unsigned char*)(ws + off_part);
    float* ML = (float*)(ws + off_ml);

    __shared__ char kbuf[2][4096];   // K tile k-major [16 k8][32 j][8], linear
    __shared__ char vbuf[2][4096];   // V tile [4 oct][128 c][8], linear

    int L = blockIdx.x;
    int npairs = B_ * nchunk;
    int pair = L % npairs, qt = L / npairs;
    int b = pair / nchunk, cz = pair % nchunk;
    int per = 128 / nchunk, rem = 128 % nchunk;
    int jb_t = per * cz + (cz < rem ? cz : rem);
    int sz_t = per + (cz < rem ? 1 : 0);
    int jb = jb_t << 5, je = jb + (sz_t << 5);

    int w = threadIdx.x >> 6, l = threadIdx.x & 63;
    int cl = l & 31, hi = l >> 5;
    int q0 = qt * 128 + w * 32;

    auto STAGE = [&](int pb_, int j0_) {
        {
            const char* src = (const char*)Kt +
                (((size_t)b * (N_ / 32) + (j0_ >> 5)) << 12) + w * 1024 + (l << 4);
            gload_lds16(src, &kbuf[pb_][w * 1024]);
        }
        {
            const char* src = (const char*)Gt +
                (((size_t)b * (N_ / 32) + (j0_ >> 5)) << 12) + w * 1024 + (l << 4);
            gload_lds16(src, &vbuf[pb_][w * 1024]);
        }
    };

    // Q fp8 as B-operand: lane holds Q[k = st*16 + hi*8 + e][q = q0+cl]
    long qf[8];
    {
        const char* qrow = (const char*)Qf + ((size_t)b * N_ + q0 + cl) * 128 + hi * 8;
#pragma unroll
        for (int st = 0; st < 8; st++) qf[st] = *(const long*)(qrow + st * 16);
    }

    f32x16 oacc[4] = {};
    float m_i = 0.f, lsum = 0.f, negmc = 0.f;

    STAGE(0, jb);
    __syncthreads();
    int pb = 0;

    for (int j0 = jb; j0 < je; j0 += 32) {
        if (j0 + 32 < je) STAGE(pb ^ 1, j0 + 32);
        const char* kb = kbuf[pb];
        const char* vbb = vbuf[pb];
        // S^T[j][q] (x16 scale) : A = K fp8 (k-major LDS), B = Q fp8 regs
        f32x16 s = {};
        __builtin_amdgcn_s_setprio(1);
#pragma unroll
        for (int st = 0; st < 8; st++) {
            long kf = *(const long*)(kb + (((st << 1) + hi) << 8) + (cl << 3));
            s = mfma32f8(kf, qf[st], s);
        }
        __builtin_amdgcn_s_setprio(0);
        if (j0 == jb) {
            float t0 = fmaxf(fmaxf(s[0], s[1]), fmaxf(s[2], s[3]));
            float t1 = fmaxf(fmaxf(s[4], s[5]), fmaxf(s[6], s[7]));
            float t2 = fmaxf(fmaxf(s[8], s[9]), fmaxf(s[10], s[11]));
            float t3 = fmaxf(fmaxf(s[12], s[13]), fmaxf(s[14], s[15]));
            float tm = fmaxf(fmaxf(t0, t1), fmaxf(t2, t3));
            tm = fmaxf(tm, __shfl_xor(tm, 32));
            m_i = tm;
            negmc = -m_i * 0.0625f;
        }
        // p = exp2(s/16 - m/16)
#pragma unroll
        for (int r = 0; r < 16; r++) s[r] = fexp2(fmaf(s[r], 0.0625f, negmc));
        lsum += ((s[0] + s[1]) + (s[2] + s[3])) + ((s[4] + s[5]) + (s[6] + s[7]))
              + ((s[8] + s[9]) + (s[10] + s[11])) + ((s[12] + s[13]) + (s[14] + s[15]));
        // pack P -> fp8 A-frags (element order = D-reg order, pi-relabel)
        long pa01[2];
        {
            int u0 = __builtin_amdgcn_cvt_pk_fp8_f32(s[0], s[1], 0, false);
            u0     = __builtin_amdgcn_cvt_pk_fp8_f32(s[2], s[3], u0, true);
            int u1 = __builtin_amdgcn_cvt_pk_fp8_f32(s[4], s[5], 0, false);
            u1     = __builtin_amdgcn_cvt_pk_fp8_f32(s[6], s[7], u1, true);
            pa01[0] = (long)(((unsigned long long)(unsigned int)u1 << 32) |
                             (unsigned int)u0);
            int u2 = __builtin_amdgcn_cvt_pk_fp8_f32(s[8], s[9], 0, false);
            u2     = __builtin_amdgcn_cvt_pk_fp8_f32(s[10], s[11], u2, true);
            int u3 = __builtin_amdgcn_cvt_pk_fp8_f32(s[12], s[13], 0, false);
            u3     = __builtin_amdgcn_cvt_pk_fp8_f32(s[14], s[15], u3, true);
            pa01[1] = (long)(((unsigned long long)(unsigned int)u3 << 32) |
                             (unsigned int)u2);
        }
        // PV: V fp8 from LDS; element e: j = u*16 + (e&3) + 8*(e>>2) + 4*hi
        __builtin_amdgcn_s_setprio(1);
#pragma unroll
        for (int u = 0; u < 2; u++) {
            long pa = pa01[u];
#pragma unroll
            for (int cb = 0; cb < 4; cb++) {
                int c = cb * 32 + cl;
                unsigned int vlo = *(const unsigned int*)(vbb + ((u << 1) << 10) +
                                                          (c << 3) + (hi << 2));
                unsigned int vhi = *(const unsigned int*)(vbb + (((u << 1) | 1) << 10) +
                                                          (c << 3) + (hi << 2));
                long vf = (long)(((unsigned long long)vhi << 32) | vlo);
                oacc[cb] = mfma32f8(pa, vf, oacc[cb]);
            }
        }
        __builtin_amdgcn_s_setprio(0);
        __syncthreads();
        pb ^= 1;
    }
    lsum += __shfl_xor(lsum, 32);
    // write fp8 partial O (scaled /16; x4096 recovered in combine) + (m,l)
#pragma unroll
    for (int cb = 0; cb < 4; cb++) {
#pragma unroll
        for (int r = 0; r < 16; r++) {
            int q = q0 + (r & 3) + 8 * (r >> 2) + 4 * hi;
            OP[((size_t)(cz * B_ + b) * N_ + q) * CI_ + cb * 32 + cl] =
                f2fp8(oacc[cb][r] * 0.0625f);
        }
    }
    if (l < 32) {
        size_t mi = ((size_t)(cz * B_ + b) * N_ + q0 + l) * 2;
        ML[mi] = m_i * 0.0625f;     // true log2 units for cross-chunk combine
        ML[mi + 1] = lsum;
    }
}

// ---------------- combine fp8 split-KV partials -> O (bf16) ----------------
template <int NC>
__global__ __launch_bounds__(256) void combine(char* ws,
                                               unsigned long long off_part,
                                               unsigned long long off_ml) {
    const unsigned char* OP = (const unsigned char*)(ws + off_part);
    const float* ML = (const float*)(ws + off_ml);
    __hip_bfloat16* O = (__hip_bfloat16*)(ws + OFF_O);
    int idx = blockIdx.x * 256 + threadIdx.x;      // B*N*16 threads
    int cg = idx & 15, n = (idx >> 4) & (N_ - 1), b = idx >> 16;
    float mz[NC], lz[NC], M = -1e30f;
#pragma unroll
    for (int z = 0; z < NC; z++) {
        size_t mi = ((size_t)(z * B_ + b) * N_ + n) * 2;
        mz[z] = ML[mi]; lz[z] = ML[mi + 1];
        M = fmaxf(M, mz[z]);
    }
    float Lsum = 0.f, wz[NC];
#pragma unroll
    for (int z = 0; z < NC; z++) { wz[z] = fexp2(mz[z] - M); Lsum += lz[z] * wz[z]; }
    float inv = 4096.0f / Lsum;     // 4096 = fp16-frame (x256) * storage (x16)
    float o[8] = {};
#pragma unroll
    for (int z = 0; z < NC; z++) {
        unsigned long long v8 = *(const unsigned long long*)(
            OP + ((size_t)(z * B_ + b) * N_ + n) * CI_ + cg * 8);
        float wv = wz[z] * inv;
#pragma unroll
        for (int i = 0; i < 8; i++)
            o[i] += wv * fp8q((unsigned int)((v8 >> (8 * i)) & 0xffull));
    }
    s16x8 r;
#pragma unroll
    for (int i = 0; i < 8; i++) {
        __hip_bfloat16 h = __float2bfloat16(o[i]);
        r[i] = *(short*)&h;
    }
    *(s16x8*)(O + ((size_t)b * N_ + n) * CI_ + cg * 8) = r;
}

// ---------------- out projection + bias + residual (frozen from R16) -------
__global__ __launch_bounds__(256) void gemm_out(const float* x, char* ws, float* y) {
    const __hip_bfloat16* Ob = (const __hip_bfloat16*)(ws + OFF_O);
    const __hip_bfloat16* Wo = (const __hip_bfloat16*)(ws + OFF_WOUT);
    const float* Bout = (const float*)(ws + OFF_BOUT);
    int b = blockIdx.y;
    int w = threadIdx.x >> 6, l = threadIdx.x & 63, lr = l & 15, lg = l >> 4;
    int n0 = blockIdx.x * 32;
    int o0 = w * 64;
    f32x4 acc[4][2] = {};   // [of][nf]
#pragma unroll
    for (int kk = 0; kk < 4; kk++) {
        s16x8 bb[2];
#pragma unroll
        for (int nf = 0; nf < 2; nf++)
            bb[nf] = ld8(Ob + (size_t)(b * N_ + n0 + 16 * nf + lr) * CI_ + kk * 32 + lg * 8);
#pragma unroll
        for (int of = 0; of < 4; of++) {
            s16x8 a = ld8(Wo + (size_t)(o0 + 16 * of + lr) * CI_ + kk * 32 + lg * 8);
#pragma unroll
            for (int nf = 0; nf < 2; nf++)
                acc[of][nf] = mfma16(a, bb[nf], acc[of][nf]);
        }
    }
#pragma unroll
    for (int of = 0; of < 4; of++) {
#pragma unroll
        for (int i = 0; i < 4; i++) {
            int o = o0 + 16 * of + lg * 4 + i;
            float bias = Bout[o];
#pragma unroll
            for (int nf = 0; nf < 2; nf++) {
                int n = n0 + 16 * nf + lr;
                size_t idx = (size_t)(b * C_ + o) * N_ + n;
                y[idx] = acc[of][nf][i] + bias + x[idx];
            }
        }
    }
}

extern "C" void kernel_launch(void* const* d_in, const int* in_sizes, int n_in,
                              void* d_out, int out_size, void* d_ws, size_t ws_size,
                              hipStream_t stream) {
    const float* x  = (const float*)d_in[0];
    const float* wg = (const float*)d_in[1];
    const float* bg = (const float*)d_in[2];
    const float* wt = (const float*)d_in[3];
    const float* bt = (const float*)d_in[4];
    const float* wp = (const float*)d_in[5];
    const float* bp = (const float*)d_in[6];
    const float* wo = (const float*)d_in[7];
    const float* bo = (const float*)d_in[8];
    char* ws = (char*)d_ws;
    float* y = (float*)d_out;

    // split-KV factor: 8 -> 1024 flash blocks = exactly 4/CU (16 waves/CU)
    unsigned long long need8 = OFF_END + (32ull << 20) + (2ull << 20);
    unsigned long long need4 = OFF_END + (16ull << 20) + (1ull << 20);
    int nchunk;
    unsigned long long off_part, off_ml;
    if (ws_size >= need8) {
        nchunk = 8; off_part = OFF_END; off_ml = OFF_END + (32ull << 20);
    } else if (ws_size >= need4) {
        nchunk = 4; off_part = OFF_END; off_ml = OFF_END + (16ull << 20);
    } else {
        nchunk = 2; off_part = 0ull; off_ml = OFF_END;
    }

    prep_weights<<<256, 256, 0, stream>>>(wg, bg, wt, bt, wp, bp, wo, bo, ws);
    proj<<<dim3(128, 4), 256, 0, stream>>>(x, ws);
    flashf8b<<<dim3(32 * B_ * nchunk), 256, 0, stream>>>(ws, nchunk, off_part, off_ml);
    if (nchunk == 8)      combine<8><<<1024, 256, 0, stream>>>(ws, off_part, off_ml);
    else if (nchunk == 4) combine<4><<<1024, 256, 0, stream>>>(ws, off_part, off_ml);
    else                  combine<2><<<1024, 256, 0, stream>>>(ws, off_part, off_ml);
    gemm_out<<<dim3(128, 4), 256, 0, stream>>>(x, ws, y);
}

// Round 20
// 81.583 us; speedup vs baseline: 8.3404x; 1.0342x over previous
//
#include <hip/hip_runtime.h>
#include <hip/hip_bf16.h>
#include <hip/hip_fp16.h>

// NonLocal block == flash attention (4 heads, N=4096, D=128) + 1x1-conv GEMMs.
// Round 20: combine + gemm_out fused (out_fused3): fp8 partials combined into
// a swizzled LDS bf16 tile (Phase A), out-GEMM from LDS (Phase B). Deletes the
// 8 MB O round-trip and one launch. flash/proj/prep frozen from R19.

typedef float f32x4 __attribute__((ext_vector_type(4)));
typedef float f32x16 __attribute__((ext_vector_type(16)));
typedef short s16x8 __attribute__((ext_vector_type(8)));

#define B_  4
#define C_  256
#define CI_ 128
#define N_  4096

// workspace layout (bytes)
#define OFF_Q    (8ull  << 20)           // fp8 [B][N][128]   2 MB (theta^T, scaled x16*rs*log2e)
#define OFF_K    (12ull << 20)           // fp8 tiled [B][N/32][16 k8][32 j][8]  2 MB
#define OFF_G    (16ull << 20)           // fp8 tiled [B][N/32][4 oct][128 c][8] 2 MB
#define OFF_WQK  (24ull << 20)
#define OFF_WG   (OFF_WQK + 131072)
#define OFF_WOUT (OFF_WG  + 65536)
#define OFF_BQK  (OFF_WOUT + 65536)
#define OFF_BG   (OFF_BQK + 1024)
#define OFF_BOUT (OFF_BG  + 512)
#define OFF_END  (OFF_BOUT + 1024)       // = 25430528

__device__ inline f32x4 mfma16(s16x8 a, s16x8 b, f32x4 c) {
    return __builtin_amdgcn_mfma_f32_16x16x32_bf16(a, b, c, 0, 0, 0);
}
__device__ inline f32x16 mfma32f8(long a, long b, f32x16 c) {
    return __builtin_amdgcn_mfma_f32_32x32x16_fp8_fp8(a, b, c, 0, 0, 0);
}
__device__ inline s16x8 ld8(const __hip_bfloat16* p) { return *(const s16x8*)p; }
__device__ inline float b2f(short u) {
    return __uint_as_float(((unsigned int)(unsigned short)u) << 16);
}
__device__ inline unsigned int pk2(float a, float b) {
    __hip_bfloat162 h;
    h.x = __float2bfloat16(a); h.y = __float2bfloat16(b);
    return *(unsigned int*)&h;
}
__device__ inline unsigned char f2fp8(float v) {
    int r = __builtin_amdgcn_cvt_pk_fp8_f32(v, v, 0, false);
    return (unsigned char)(r & 0xff);
}
// fp8 e4m3 byte -> f32 * (1/256): place bits in fp16 frame (handles denormals)
__device__ inline float fp8q(unsigned int byte) {
    union { unsigned short u; __half h; } cv;
    cv.u = (unsigned short)(((byte & 0x80u) << 8) | ((byte & 0x7fu) << 7));
    return __half2float(cv.h);
}
__device__ inline void gload_lds16(const void* g, void* l) {
    __builtin_amdgcn_global_load_lds(
        (const __attribute__((address_space(1))) unsigned int*)g,
        (__attribute__((address_space(3))) unsigned int*)l, 16, 0, 0);
}
__device__ inline float fexp2(float x) { return __builtin_amdgcn_exp2f(x); }

// ---------------- weight prep: theta scaled by 16*rs*log2e (fp8 headroom) --
__global__ void prep_weights(const float* wg, const float* bg,
                             const float* wt, const float* bt,
                             const float* wp, const float* bp,
                             const float* wo, const float* bo, char* ws) {
    __hip_bfloat16* Wqk  = (__hip_bfloat16*)(ws + OFF_WQK);
    __hip_bfloat16* Wg   = (__hip_bfloat16*)(ws + OFF_WG);
    __hip_bfloat16* Wout = (__hip_bfloat16*)(ws + OFF_WOUT);
    float* Bqk  = (float*)(ws + OFF_BQK);
    float* Bg   = (float*)(ws + OFF_BG);
    float* Bout = (float*)(ws + OFF_BOUT);
    const float rs16 = 0.08838834764831845f * 1.4426950408889634f * 16.0f;
    int idx = blockIdx.x * 256 + threadIdx.x;
    if (idx < 65536) {
        int r = idx >> 8, c = idx & 255;
        float v = (r < 128) ? wt[r * 256 + c] * rs16 : wp[(r - 128) * 256 + c];
        Wqk[idx] = __float2bfloat16(v);
    }
    if (idx < 32768) {
        Wg[idx]   = __float2bfloat16(wg[idx]);
        Wout[idx] = __float2bfloat16(wo[idx]);
    }
    if (idx < 256) { Bqk[idx] = (idx < 128) ? bt[idx] * rs16 : bp[idx - 128]; Bout[idx] = bo[idx]; }
    if (idx < 128) Bg[idx] = bg[idx];
}

// ---------------- fused transpose + projection; Q/K/G written as fp8 -------
__global__ __launch_bounds__(256) void proj(const float* x, char* ws) {
    const __hip_bfloat16* Wqk = (const __hip_bfloat16*)(ws + OFF_WQK);
    const __hip_bfloat16* Wg  = (const __hip_bfloat16*)(ws + OFF_WG);
    const float* Bqk = (const float*)(ws + OFF_BQK);
    const float* Bg  = (const float*)(ws + OFF_BG);
    unsigned char* Qf = (unsigned char*)(ws + OFF_Q);
    unsigned char* Kt = (unsigned char*)(ws + OFF_K);
    unsigned char* Gt = (unsigned char*)(ws + OFF_G);

    __shared__ char at[32 * 512];   // [32 n][256 c] bf16, 16B slots XOR-swizzled

    int b = blockIdx.y, n0 = blockIdx.x * 32;
    int t = threadIdx.x;
    int w = t >> 6, l = t & 63, lr = l & 15, lg = l >> 4;

    {
        int n4 = (t & 7) * 4;
        int cp = t >> 3;
        const float* xb = x + ((size_t)b * C_) * N_ + n0 + n4;
#pragma unroll
        for (int p = 0; p < 4; p++) {
            int c0 = (p * 32 + cp) * 2;
            f32x4 vA = *(const f32x4*)(xb + (size_t)c0 * N_);
            f32x4 vB = *(const f32x4*)(xb + (size_t)(c0 + 1) * N_);
            int slot = c0 >> 3, coff = (c0 & 7) << 1;
#pragma unroll
            for (int i = 0; i < 4; i++) {
                int n = n4 + i;
                *(unsigned int*)(&at[n * 512 + ((slot ^ (n & 7)) << 4) + coff]) =
                    pk2(vA[i], vB[i]);
            }
        }
    }
    __syncthreads();

    f32x4 acc[4][2] = {};    // QK path: [of][nf]
    f32x4 accg[2][2] = {};   // G  path: [og][nf]
    int o0q = w * 64, o0g = w * 32;
#pragma unroll
    for (int kk = 0; kk < 8; kk++) {
        s16x8 a[2];
#pragma unroll
        for (int nf = 0; nf < 2; nf++) {
            int row = nf * 16 + lr;
            int s = (4 * kk + lg) ^ (row & 7);
            a[nf] = *(const s16x8*)(&at[row * 512 + s * 16]);
        }
#pragma unroll
        for (int of = 0; of < 4; of++) {
            s16x8 bb = ld8(Wqk + (size_t)(o0q + 16 * of + lr) * C_ + kk * 32 + lg * 8);
            acc[of][0] = mfma16(a[0], bb, acc[of][0]);
            acc[of][1] = mfma16(a[1], bb, acc[of][1]);
        }
#pragma unroll
        for (int og = 0; og < 2; og++) {
            s16x8 ag = ld8(Wg + (size_t)(o0g + 16 * og + lr) * C_ + kk * 32 + lg * 8);
            accg[og][0] = mfma16(ag, a[0], accg[og][0]);
            accg[og][1] = mfma16(ag, a[1], accg[og][1]);
        }
    }
    // QK epilogue -> fp8. Q: [b][n][o]. K: tiled [b][n>>5][k8][n&31][e]
#pragma unroll
    for (int of = 0; of < 4; of++) {
        int o = o0q + 16 * of + lr;
        float bias = Bqk[o];
#pragma unroll
        for (int nf = 0; nf < 2; nf++) {
#pragma unroll
            for (int i = 0; i < 4; i++) {
                int n = n0 + 16 * nf + lg * 4 + i;
                float v = acc[of][nf][i] + bias;
                unsigned char u8 = f2fp8(v);
                if (o < 128) {
                    Qf[((size_t)b * N_ + n) * 128 + o] = u8;
                } else {
                    int op = o - 128;
                    size_t a2 = (((size_t)b * (N_ / 32) + (n >> 5)) << 12) +
                                ((op >> 3) << 8) + ((n & 31) << 3) + (op & 7);
                    Kt[a2] = u8;
                }
            }
        }
    }
    // G epilogue -> fp8 tiled: [b][n>>5][(n&31)>>3][c][n&7]
#pragma unroll
    for (int og = 0; og < 2; og++) {
#pragma unroll
        for (int i = 0; i < 4; i++) {
            int o = o0g + 16 * og + lg * 4 + i;   // c
            float bias = Bg[o];
#pragma unroll
            for (int nf = 0; nf < 2; nf++) {
                int n = n0 + 16 * nf + lr;
                float v = accg[og][nf][i] + bias;
                size_t a3 = (((size_t)b * (N_ / 32) + (n >> 5)) << 12) +
                            (((n & 31) >> 3) << 10) + (o << 3) + (n & 7);
                Gt[a3] = f2fp8(v);
            }
        }
    }
}

// ---------------- flash fp8: fp8 QK + fp8 PV + fp8 partials (frozen) -------
__global__ __launch_bounds__(256, 4) void flashf8b(char* ws, int nchunk,
                                                   unsigned long long off_part,
                                                   unsigned long long off_ml) {
    const unsigned char* Qf = (const unsigned char*)(ws + OFF_Q);
    const unsigned char* Kt = (const unsigned char*)(ws + OFF_K);
    const unsigned char* Gt = (const unsigned char*)(ws + OFF_G);
    unsigned char* OP = (unsigned char*)(ws + off_part);
    float* ML = (float*)(ws + off_ml);

    __shared__ char kbuf[2][4096];   // K tile k-major [16 k8][32 j][8], linear
    __shared__ char vbuf[2][4096];   // V tile [4 oct][128 c][8], linear

    int L = blockIdx.x;
    int npairs = B_ * nchunk;
    int pair = L % npairs, qt = L / npairs;
    int b = pair / nchunk, cz = pair % nchunk;
    int per = 128 / nchunk, rem = 128 % nchunk;
    int jb_t = per * cz + (cz < rem ? cz : rem);
    int sz_t = per + (cz < rem ? 1 : 0);
    int jb = jb_t << 5, je = jb + (sz_t << 5);

    int w = threadIdx.x >> 6, l = threadIdx.x & 63;
    int cl = l & 31, hi = l >> 5;
    int q0 = qt * 128 + w * 32;

    auto STAGE = [&](int pb_, int j0_) {
        {
            const char* src = (const char*)Kt +
                (((size_t)b * (N_ / 32) + (j0_ >> 5)) << 12) + w * 1024 + (l << 4);
            gload_lds16(src, &kbuf[pb_][w * 1024]);
        }
        {
            const char* src = (const char*)Gt +
                (((size_t)b * (N_ / 32) + (j0_ >> 5)) << 12) + w * 1024 + (l << 4);
            gload_lds16(src, &vbuf[pb_][w * 1024]);
        }
    };

    // Q fp8 as B-operand: lane holds Q[k = st*16 + hi*8 + e][q = q0+cl]
    long qf[8];
    {
        const char* qrow = (const char*)Qf + ((size_t)b * N_ + q0 + cl) * 128 + hi * 8;
#pragma unroll
        for (int st = 0; st < 8; st++) qf[st] = *(const long*)(qrow + st * 16);
    }

    f32x16 oacc[4] = {};
    float m_i = 0.f, lsum = 0.f, negmc = 0.f;

    STAGE(0, jb);
    __syncthreads();
    int pb = 0;

    for (int j0 = jb; j0 < je; j0 += 32) {
        if (j0 + 32 < je) STAGE(pb ^ 1, j0 + 32);
        const char* kb = kbuf[pb];
        const char* vbb = vbuf[pb];
        // S^T[j][q] (x16 scale) : A = K fp8 (k-major LDS), B = Q fp8 regs
        f32x16 s = {};
        __builtin_amdgcn_s_setprio(1);
#pragma unroll
        for (int st = 0; st < 8; st++) {
            long kf = *(const long*)(kb + (((st << 1) + hi) << 8) + (cl << 3));
            s = mfma32f8(kf, qf[st], s);
        }
        __builtin_amdgcn_s_setprio(0);
        if (j0 == jb) {
            float t0 = fmaxf(fmaxf(s[0], s[1]), fmaxf(s[2], s[3]));
            float t1 = fmaxf(fmaxf(s[4], s[5]), fmaxf(s[6], s[7]));
            float t2 = fmaxf(fmaxf(s[8], s[9]), fmaxf(s[10], s[11]));
            float t3 = fmaxf(fmaxf(s[12], s[13]), fmaxf(s[14], s[15]));
            float tm = fmaxf(fmaxf(t0, t1), fmaxf(t2, t3));
            tm = fmaxf(tm, __shfl_xor(tm, 32));
            m_i = tm;
            negmc = -m_i * 0.0625f;
        }
        // p = exp2(s/16 - m/16)
#pragma unroll
        for (int r = 0; r < 16; r++) s[r] = fexp2(fmaf(s[r], 0.0625f, negmc));
        lsum += ((s[0] + s[1]) + (s[2] + s[3])) + ((s[4] + s[5]) + (s[6] + s[7]))
              + ((s[8] + s[9]) + (s[10] + s[11])) + ((s[12] + s[13]) + (s[14] + s[15]));
        // pack P -> fp8 A-frags (element order = D-reg order, pi-relabel)
        long pa01[2];
        {
            int u0 = __builtin_amdgcn_cvt_pk_fp8_f32(s[0], s[1], 0, false);
            u0     = __builtin_amdgcn_cvt_pk_fp8_f32(s[2], s[3], u0, true);
            int u1 = __builtin_amdgcn_cvt_pk_fp8_f32(s[4], s[5], 0, false);
            u1     = __builtin_amdgcn_cvt_pk_fp8_f32(s[6], s[7], u1, true);
            pa01[0] = (long)(((unsigned long long)(unsigned int)u1 << 32) |
                             (unsigned int)u0);
            int u2 = __builtin_amdgcn_cvt_pk_fp8_f32(s[8], s[9], 0, false);
            u2     = __builtin_amdgcn_cvt_pk_fp8_f32(s[10], s[11], u2, true);
            int u3 = __builtin_amdgcn_cvt_pk_fp8_f32(s[12], s[13], 0, false);
            u3     = __builtin_amdgcn_cvt_pk_fp8_f32(s[14], s[15], u3, true);
            pa01[1] = (long)(((unsigned long long)(unsigned int)u3 << 32) |
                             (unsigned int)u2);
        }
        // PV: V fp8 from LDS; element e: j = u*16 + (e&3) + 8*(e>>2) + 4*hi
        __builtin_amdgcn_s_setprio(1);
#pragma unroll
        for (int u = 0; u < 2; u++) {
            long pa = pa01[u];
#pragma unroll
            for (int cb = 0; cb < 4; cb++) {
                int c = cb * 32 + cl;
                unsigned int vlo = *(const unsigned int*)(vbb + ((u << 1) << 10) +
                                                          (c << 3) + (hi << 2));
                unsigned int vhi = *(const unsigned int*)(vbb + (((u << 1) | 1) << 10) +
                                                          (c << 3) + (hi << 2));
                long vf = (long)(((unsigned long long)vhi << 32) | vlo);
                oacc[cb] = mfma32f8(pa, vf, oacc[cb]);
            }
        }
        __builtin_amdgcn_s_setprio(0);
        __syncthreads();
        pb ^= 1;
    }
    lsum += __shfl_xor(lsum, 32);
    // write fp8 partial O (scaled /16; x4096 recovered in epilogue) + (m,l)
#pragma unroll
    for (int cb = 0; cb < 4; cb++) {
#pragma unroll
        for (int r = 0; r < 16; r++) {
            int q = q0 + (r & 3) + 8 * (r >> 2) + 4 * hi;
            OP[((size_t)(cz * B_ + b) * N_ + q) * CI_ + cb * 32 + cl] =
                f2fp8(oacc[cb][r] * 0.0625f);
        }
    }
    if (l < 32) {
        size_t mi = ((size_t)(cz * B_ + b) * N_ + q0 + l) * 2;
        ML[mi] = m_i * 0.0625f;     // true log2 units for cross-chunk combine
        ML[mi + 1] = lsum;
    }
}

// ------- fused epilogue v3: combine fp8 partials (LDS) + out-GEMM ----------
// grid (256, B_) = 1024 blocks, 256 threads. Block = 16 n x 256 o.
// Phase A: combine NC fp8 partials -> swizzled LDS bf16 tile (coalesced u64
// reads). Phase B: out-GEMM with B-frags from LDS; bias + residual; fp32 out.
template <int NC>
__global__ __launch_bounds__(256) void out_fused3(const float* x, char* ws, float* y,
                                                  unsigned long long off_part,
                                                  unsigned long long off_ml) {
    const unsigned char* OP = (const unsigned char*)(ws + off_part);
    const float* ML = (const float*)(ws + off_ml);
    const __hip_bfloat16* Wo = (const __hip_bfloat16*)(ws + OFF_WOUT);
    const float* Bout = (const float*)(ws + OFF_BOUT);

    __shared__ char oT[16 * 256];   // [16 n][128 c] bf16, 16B slots swizzled

    int b = blockIdx.y;
    int n0 = blockIdx.x * 16;
    int t = threadIdx.x;

    // Phase A: combine fp8 partials for this 16n x 128c tile
    {
        int nl = t >> 4;           // 0..15
        int cg = t & 15;           // 0..15 octet slots (8 c each)
        int n = n0 + nl;
        float mz[NC], lz[NC], M = -1e30f;
#pragma unroll
        for (int z = 0; z < NC; z++) {
            size_t mi = ((size_t)(z * B_ + b) * N_ + n) * 2;
            mz[z] = ML[mi]; lz[z] = ML[mi + 1];
            M = fmaxf(M, mz[z]);
        }
        float Ls = 0.f, wz[NC];
#pragma unroll
        for (int z = 0; z < NC; z++) { wz[z] = fexp2(mz[z] - M); Ls += lz[z] * wz[z]; }
        float inv = 4096.0f / Ls;   // 4096 = fp16-frame (x256) * storage (x16)
        float o8[8] = {};
#pragma unroll
        for (int z = 0; z < NC; z++) {
            unsigned long long v8 = *(const unsigned long long*)(
                OP + ((size_t)(z * B_ + b) * N_ + n) * CI_ + cg * 8);
            float wv = wz[z] * inv;
#pragma unroll
            for (int i = 0; i < 8; i++)
                o8[i] += wv * fp8q((unsigned int)((v8 >> (8 * i)) & 0xffull));
        }
        union { unsigned int u[4]; s16x8 v; } r;
#pragma unroll
        for (int e = 0; e < 4; e++) r.u[e] = pk2(o8[2 * e], o8[2 * e + 1]);
        *(s16x8*)(&oT[nl * 256 + ((cg ^ (nl & 7)) << 4)]) = r.v;
    }
    __syncthreads();

    // Phase B: out-GEMM; wave w owns o = w*64 .. w*64+63, all 16 n
    int w = t >> 6, l = t & 63, lr = l & 15, lg = l >> 4;
    int o0 = w * 64;
    f32x4 acc[4] = {};
#pragma unroll
    for (int kk = 0; kk < 4; kk++) {
        int slot = kk * 4 + lg;
        s16x8 bb = *(const s16x8*)(&oT[lr * 256 + ((slot ^ (lr & 7)) << 4)]);
#pragma unroll
        for (int of = 0; of < 4; of++) {
            s16x8 a = ld8(Wo + (size_t)(o0 + 16 * of + lr) * CI_ + kk * 32 + lg * 8);
            acc[of] = mfma16(a, bb, acc[of]);
        }
    }
#pragma unroll
    for (int of = 0; of < 4; of++) {
#pragma unroll
        for (int i = 0; i < 4; i++) {
            int o = o0 + 16 * of + lg * 4 + i;
            int n = n0 + lr;
            size_t idx = (size_t)(b * C_ + o) * N_ + n;
            y[idx] = acc[of][i] + Bout[o] + x[idx];
        }
    }
}

extern "C" void kernel_launch(void* const* d_in, const int* in_sizes, int n_in,
                              void* d_out, int out_size, void* d_ws, size_t ws_size,
                              hipStream_t stream) {
    const float* x  = (const float*)d_in[0];
    const float* wg = (const float*)d_in[1];
    const float* bg = (const float*)d_in[2];
    const float* wt = (const float*)d_in[3];
    const float* bt = (const float*)d_in[4];
    const float* wp = (const float*)d_in[5];
    const float* bp = (const float*)d_in[6];
    const float* wo = (const float*)d_in[7];
    const float* bo = (const float*)d_in[8];
    char* ws = (char*)d_ws;
    float* y = (float*)d_out;

    // split-KV factor: 8 -> 1024 flash blocks = exactly 4/CU (16 waves/CU)
    unsigned long long need8 = OFF_END + (32ull << 20) + (2ull << 20);
    unsigned long long need4 = OFF_END + (16ull << 20) + (1ull << 20);
    int nchunk;
    unsigned long long off_part, off_ml;
    if (ws_size >= need8) {
        nchunk = 8; off_part = OFF_END; off_ml = OFF_END + (32ull << 20);
    } else if (ws_size >= need4) {
        nchunk = 4; off_part = OFF_END; off_ml = OFF_END + (16ull << 20);
    } else {
        nchunk = 2; off_part = 0ull; off_ml = OFF_END;
    }

    prep_weights<<<256, 256, 0, stream>>>(wg, bg, wt, bt, wp, bp, wo, bo, ws);
    proj<<<dim3(128, 4), 256, 0, stream>>>(x, ws);
    flashf8b<<<dim3(32 * B_ * nchunk), 256, 0, stream>>>(ws, nchunk, off_part, off_ml);
    if (nchunk == 8)
        out_fused3<8><<<dim3(256, 4), 256, 0, stream>>>(x, ws, y, off_part, off_ml);
    else if (nchunk == 4)
        out_fused3<4><<<dim3(256, 4), 256, 0, stream>>>(x, ws, y, off_part, off_ml);
    else
        out_fused3<2><<<dim3(256, 4), 256, 0, stream>>>(x, ws, y, off_part, off_ml);
}